// Round 11
// baseline (294.472 us; speedup 1.0000x reference)
//
#include <hip/hip_runtime.h>
#include <hip/hip_fp16.h>
#include <math.h>

// ---------------------------------------------------------------------------
// GCN: 3x (MFMA-fp16 GEMM -> sym-normalized neighbor aggregate) with SiLU,
// then per-graph max+mean pool and log_softmax.
// CSR build = 2-pass bucket sort (round-6 structure).
// Round 11: UNPADDED gather tables. 96 fp16 = 192 B = exactly 3 aligned 64B
// lines per row (no pad fetch, table 19.2MB not 25.6MB). Lane li<12 of each
// 16-lane group loads octet li; li>=12 clamps to octet li-12 (same-row
// broadcast, no extra lines; garbage stays in garbage lanes, never written).
// GEMM output = natural [N][96] fp16 (same layout as agg output).
// adj loads + agg stores nontemporal (protect table L2 residency).
// ---------------------------------------------------------------------------

typedef _Float16 f16x8 __attribute__((ext_vector_type(8)));
typedef _Float16 f16x4 __attribute__((ext_vector_type(4)));
typedef float f32x4 __attribute__((ext_vector_type(4)));

static __device__ __forceinline__ float silu_f(float v) {
    return v / (1.0f + __expf(-v));
}

// --- int64-vs-int32 input detection -----------------------------------------
__global__ __launch_bounds__(256) void k_detect(const int* __restrict__ raw,
                                                int* __restrict__ flag) {
    __shared__ int anynz;
    if (threadIdx.x == 0) anynz = 0;
    __syncthreads();
    if (raw[2 * threadIdx.x + 1] != 0) anynz = 1;  // benign race, same value
    __syncthreads();
    if (threadIdx.x == 0) *flag = (anynz ? 0 : 1); // 1 => int64
}

__global__ __launch_bounds__(256) void k_convert(const int* __restrict__ raw,
                                                 int* __restrict__ out,
                                                 const int* __restrict__ flag,
                                                 int count) {
    int i = blockIdx.x * 256 + threadIdx.x;
    if (i < count) out[i] = flag[0] ? raw[2 * i] : raw[i];
}

// --- CSR pass 1: bucket histogram (bucket = dst>>8, <=512 buckets) -----------
__global__ __launch_bounds__(512) void k_p1hist(const int* __restrict__ dst,
                                                int* __restrict__ bcnt,
                                                int E, int nbuk) {
    __shared__ int hs[512];
    const int t = threadIdx.x;
    hs[t] = 0;
    __syncthreads();
    const int base = blockIdx.x * 8192;
    const int lim = min(base + 8192, E);
    for (int j = base + t; j < lim; j += 512)
        atomicAdd(&hs[dst[j] >> 8], 1);
    __syncthreads();
    if (t < nbuk && hs[t]) atomicAdd(&bcnt[t], hs[t]);
}

// --- CSR pass 1b: exclusive scan of bucket counts -> bstart ------------------
__global__ __launch_bounds__(512) void k_bscan(const int* __restrict__ bcnt,
                                               int* __restrict__ bstart,
                                               int nbuk, int E) {
    __shared__ int lds[512];
    int t = threadIdx.x;
    int v = (t < nbuk) ? bcnt[t] : 0;
    lds[t] = v;
    __syncthreads();
    for (int off = 1; off < 512; off <<= 1) {
        int y = (t >= off) ? lds[t - off] : 0;
        __syncthreads();
        lds[t] += y;
        __syncthreads();
    }
    if (t < nbuk) bstart[t] = lds[t] - v;
    if (t == 0) bstart[nbuk] = E;
}

// --- CSR pass 2: bucket scatter, block-staged ---------------------------------
__global__ __launch_bounds__(512) void k_p2scatter(const int* __restrict__ e32,
                                                   const int* __restrict__ bstart,
                                                   int* __restrict__ gcursor,
                                                   unsigned* __restrict__ ebuk,
                                                   int E, int nbuk) {
    __shared__ int hs[512], sc[512], lexcl[512], pl[512], gb[512];
    __shared__ unsigned stg[8192];
    __shared__ unsigned short stb[8192];
    const int t = threadIdx.x;
    const int base = blockIdx.x * 8192;
    const int len = min(8192, E - base);
    const int* __restrict__ dstp = e32 + E;

    hs[t] = 0;
    __syncthreads();
    for (int j = t; j < len; j += 512)
        atomicAdd(&hs[dstp[base + j] >> 8], 1);
    __syncthreads();

    int cv = (t < nbuk) ? hs[t] : 0;
    sc[t] = cv;
    __syncthreads();
    for (int off = 1; off < 512; off <<= 1) {
        int y = (t >= off) ? sc[t - off] : 0;
        __syncthreads();
        sc[t] += y;
        __syncthreads();
    }
    int ex = sc[t] - cv;
    if (t < nbuk) {
        lexcl[t] = ex;
        pl[t] = ex;
        gb[t] = cv ? atomicAdd(&gcursor[t], cv) : 0;
    }
    __syncthreads();

    for (int j = t; j < len; j += 512) {
        int d = dstp[base + j];
        int s = e32[base + j];
        int b = d >> 8;
        int slot = atomicAdd(&pl[b], 1);
        stg[slot] = ((unsigned)s << 8) | (unsigned)(d & 255);
        stb[slot] = (unsigned short)b;
    }
    __syncthreads();

    for (int s2 = t; s2 < len; s2 += 512) {
        int b = stb[s2];
        int gpos = bstart[b] + gb[b] + (s2 - lexcl[b]);
        ebuk[gpos] = stg[s2];
    }
}

// --- CSR pass 3: per-bucket counting sort -> adj, rowptr, dinv ----------------
__global__ __launch_bounds__(256) void k_p3sort(const unsigned* __restrict__ ebuk,
                                                const int* __restrict__ bstart,
                                                int* __restrict__ adj,
                                                int* __restrict__ rowptr,
                                                float* __restrict__ dinv,
                                                int n, int E) {
    const int b = blockIdx.x;
    const int t = threadIdx.x;
    const int s0 = bstart[b], s1 = bstart[b + 1];
    __shared__ int cs[256], pl[256];
    cs[t] = 0;
    __syncthreads();
    for (int j = s0 + t; j < s1; j += 256)
        atomicAdd(&cs[ebuk[j] & 255], 1);
    __syncthreads();
    int cv = cs[t];
    pl[t] = cv;
    __syncthreads();
    for (int off = 1; off < 256; off <<= 1) {
        int y = (t >= off) ? pl[t - off] : 0;
        __syncthreads();
        pl[t] += y;
        __syncthreads();
    }
    int ex = pl[t] - cv;
    __syncthreads();
    pl[t] = ex;
    int node = (b << 8) + t;
    if (node < n) {
        rowptr[node] = s0 + ex;
        dinv[node] = rsqrtf((float)cv + 1.0f);  // +1 self loop
    }
    if (b == 0 && t == 0) rowptr[n] = E;
    __syncthreads();
    for (int j = s0 + t; j < s1; j += 256) {
        unsigned p = ebuk[j];
        int slot = atomicAdd(&pl[p & 255], 1);
        adj[s0 + slot] = (int)(p >> 8);
    }
}

// --- per-graph boundaries (batch is sorted) -----------------------------------
__global__ __launch_bounds__(256) void k_gstart(const int* __restrict__ batch,
                                                int* __restrict__ gstart,
                                                int n, int G) {
    int t = threadIdx.x;
    if (t > G) return;
    int lo = 0, hi = n;
    while (lo < hi) {
        int mid = (lo + hi) >> 1;
        if (batch[mid] < t) lo = mid + 1; else hi = mid;
    }
    gstart[t] = lo;
}

// --- W transpose + fp16 convert: WT[n][k] = fp16(W[k][n]) ---------------------
__global__ __launch_bounds__(256) void k_wt(const float* __restrict__ W,
                                            __half* __restrict__ WT, int fout) {
    int idx = blockIdx.x * 256 + threadIdx.x;
    if (idx < fout * 96) {
        int nn = idx / 96, kk = idx - nn * 96;
        WT[idx] = __float2half(W[kk * fout + nn]);
    }
}

// --- MFMA GEMM: H[r,:] = fp16( dinv[r] * (A[r,:96] @ W) ), LDS-free ----------
// A: fp32 natural (AHALF=0, layer 0 input x) or fp16 natural 96-stride
// (AHALF=1, agg output). Output: fp16 natural FOUT-stride.
// A and B share identical per-lane k-addressing -> the hardware k->slot map
// cancels (dot products are k-permutation invariant).
template <int FOUT, bool AHALF>
__global__ __launch_bounds__(256) void k_gemm_mfma(const float* __restrict__ Xf,
                                                   const __half* __restrict__ Xh,
                                                   const __half* __restrict__ WT,
                                                   const float* __restrict__ dinv,
                                                   __half* __restrict__ H, int n) {
    const int l = threadIdx.x & 63;
    const int w = threadIdx.x >> 6;
    const int row0 = blockIdx.x * 64 + w * 16;
    const int lr = l & 15, lg = l >> 4;
    constexpr int NT = FOUT / 16;

    f16x8 bfrag[NT][3];
    #pragma unroll
    for (int t = 0; t < NT; ++t)
        #pragma unroll
        for (int kk = 0; kk < 3; ++kk)
            bfrag[t][kk] = *(const f16x8*)&WT[(t * 16 + lr) * 96 + kk * 32 + lg * 8];

    f32x4 acc[NT];
    #pragma unroll
    for (int t = 0; t < NT; ++t) acc[t] = (f32x4){0.f, 0.f, 0.f, 0.f};

    int arow = row0 + lr;
    int arow_c = arow < n ? arow : n - 1;  // clamp; garbage rows never stored

    #pragma unroll
    for (int kk = 0; kk < 3; ++kk) {
        f16x8 af;
        if (AHALF) {
            af = *(const f16x8*)(Xh + (size_t)arow_c * 96 + kk * 32 + lg * 8);
        } else {
            const float* xr = Xf + (size_t)arow_c * 96;
            float4 u0 = *(const float4*)&xr[kk * 32 + lg * 8];
            float4 u1 = *(const float4*)&xr[kk * 32 + lg * 8 + 4];
            af[0] = (_Float16)u0.x; af[1] = (_Float16)u0.y;
            af[2] = (_Float16)u0.z; af[3] = (_Float16)u0.w;
            af[4] = (_Float16)u1.x; af[5] = (_Float16)u1.y;
            af[6] = (_Float16)u1.z; af[7] = (_Float16)u1.w;
        }
        #pragma unroll
        for (int t = 0; t < NT; ++t)
            acc[t] = __builtin_amdgcn_mfma_f32_16x16x32_f16(af, bfrag[t][kk], acc[t], 0, 0, 0);
    }

    // C/D: col = t*16+lr, row = row0 + lg*4 + i  (m89-verified map)
    #pragma unroll
    for (int i = 0; i < 4; ++i) {
        int r = row0 + lg * 4 + i;
        if (r < n) {
            float dv = dinv[r];
            #pragma unroll
            for (int t = 0; t < NT; ++t)
                H[(size_t)r * FOUT + t * 16 + lr] = __float2half(acc[t][i] * dv);
        }
    }
}

// --- aggregation, F=96, UNPADDED 192B rows ------------------------------------
// One wave per node. Quarter q = l>>4 owns one edge-chain; lane li = l&15:
// li<12 loads octet li (f16x8) of the row; li>=12 clamps to octet li-12
// (same-row broadcast, no extra lines; results discarded). 8 edges/iter =
// 2 gathers/lane; tail masked via the w multiplier (v_fma_mix_f32).
// Output fp16 natural [n][96], nontemporal.
template <bool SILU>
__global__ __launch_bounds__(256) void k_agg96(const __half* __restrict__ Hp,
                                               const float* __restrict__ dinv,
                                               const int* __restrict__ rowptr,
                                               const int* __restrict__ adj,
                                               const float* __restrict__ bias,
                                               __half* __restrict__ OUT, int n) {
    const int l = threadIdx.x & 63;
    const int node = blockIdx.x * 4 + (threadIdx.x >> 6);
    if (node >= n) return;
    const int q = l >> 4;
    const int li = l & 15;
    const int oct = li < 12 ? li : li - 12;   // octet within row (broadcast for pads)
    const float dn = dinv[node];
    const int e0 = rowptr[node], e1 = rowptr[node + 1];
    const f16x8* __restrict__ H8 = (const f16x8*)Hp;  // 12 f16x8 per row

    float acc[8] = {0.f, 0.f, 0.f, 0.f, 0.f, 0.f, 0.f, 0.f};

    // self row (counted once, quarter 0)
    {
        f16x8 v = H8[(size_t)node * 12 + oct];
        float ws = (q == 0) ? 1.f : 0.f;
        #pragma unroll
        for (int i = 0; i < 8; ++i) acc[i] = fmaf((float)v[i], ws, acc[i]);
    }

    for (int e = e0; e < e1; e += 8) {
        int ai = e + (l & 7);
        int v_s = __builtin_nontemporal_load(adj + (ai < e1 ? ai : e1 - 1));
        #pragma unroll
        for (int j = 0; j < 2; ++j) {
            int c = 4 * j + q;
            int s = __shfl(v_s, c, 64);
            float w = (e + c < e1) ? 1.f : 0.f;
            f16x8 v = H8[(size_t)s * 12 + oct];
            #pragma unroll
            for (int i = 0; i < 8; ++i) acc[i] = fmaf((float)v[i], w, acc[i]);
        }
    }

    // reduce across quarters (li lanes only talk to same-li lanes)
    #pragma unroll
    for (int i = 0; i < 8; ++i) {
        acc[i] += __shfl_xor(acc[i], 16, 64);
        acc[i] += __shfl_xor(acc[i], 32, 64);
    }

    if (l < 12) {  // q==0, li<12: lane li owns features 8li..8li+7
        float4 bv0 = ((const float4*)bias)[2 * l];
        float4 bv1 = ((const float4*)bias)[2 * l + 1];
        float o0 = acc[0] * dn + bv0.x, o1 = acc[1] * dn + bv0.y;
        float o2 = acc[2] * dn + bv0.z, o3 = acc[3] * dn + bv0.w;
        float o4 = acc[4] * dn + bv1.x, o5 = acc[5] * dn + bv1.y;
        float o6 = acc[6] * dn + bv1.z, o7 = acc[7] * dn + bv1.w;
        if (SILU) {
            o0 = silu_f(o0); o1 = silu_f(o1); o2 = silu_f(o2); o3 = silu_f(o3);
            o4 = silu_f(o4); o5 = silu_f(o5); o6 = silu_f(o6); o7 = silu_f(o7);
        }
        f16x8 wv = {(_Float16)o0, (_Float16)o1, (_Float16)o2, (_Float16)o3,
                    (_Float16)o4, (_Float16)o5, (_Float16)o6, (_Float16)o7};
        __builtin_nontemporal_store(wv, (f16x8*)(OUT + (size_t)node * 96 + l * 8));
    }
}

// --- aggregation, F=32, natural 64B rows --------------------------------------
// 8-lane row groups; lane li loads f16x4 (8B). g = l>>3 owns one edge-chain.
__global__ __launch_bounds__(256) void k_agg32(const __half* __restrict__ Hp,
                                               const float* __restrict__ dinv,
                                               const int* __restrict__ rowptr,
                                               const int* __restrict__ adj,
                                               const float* __restrict__ bias,
                                               float* __restrict__ OUT, int n) {
    const int l = threadIdx.x & 63;
    const int node = blockIdx.x * 4 + (threadIdx.x >> 6);
    if (node >= n) return;
    const int g = l >> 3;
    const int li = l & 7;
    const float dn = dinv[node];
    const int e0 = rowptr[node], e1 = rowptr[node + 1];
    const f16x4* __restrict__ H4 = (const f16x4*)Hp;  // 8 f16x4 per row

    float acc[4] = {0.f, 0.f, 0.f, 0.f};

    {
        f16x4 v = H4[(size_t)node * 8 + li];
        float ws = (g == 0) ? 1.f : 0.f;
        #pragma unroll
        for (int i = 0; i < 4; ++i) acc[i] = fmaf((float)v[i], ws, acc[i]);
    }

    for (int e = e0; e < e1; e += 8) {
        int ai = e + (l & 7);
        int v_s = __builtin_nontemporal_load(adj + (ai < e1 ? ai : e1 - 1));
        int src = __shfl(v_s, g, 64);
        float w = (e + g < e1) ? 1.f : 0.f;
        f16x4 v = H4[(size_t)src * 8 + li];
        #pragma unroll
        for (int i = 0; i < 4; ++i) acc[i] = fmaf((float)v[i], w, acc[i]);
    }

    #pragma unroll
    for (int i = 0; i < 4; ++i) {
        acc[i] += __shfl_xor(acc[i], 8, 64);
        acc[i] += __shfl_xor(acc[i], 16, 64);
        acc[i] += __shfl_xor(acc[i], 32, 64);
    }

    if (l < 8) {  // lane li owns features 4li..4li+3
        float4 bv = ((const float4*)bias)[l];
        f32x4 o = {acc[0] * dn + bv.x, acc[1] * dn + bv.y,
                   acc[2] * dn + bv.z, acc[3] * dn + bv.w};
        __builtin_nontemporal_store(o, (f32x4*)(OUT + (size_t)node * 32 + l * 4));
    }
}

// --- per-graph max+mean pool (block per graph) --------------------------------
__global__ __launch_bounds__(256) void k_pool(const float* __restrict__ A,
                                              const int* __restrict__ gstart,
                                              float* __restrict__ pooled) {
    int g = blockIdx.x;
    int s0 = gstart[g], s1 = gstart[g + 1];
    int c = threadIdx.x & 31, k = threadIdx.x >> 5;
    float mx = -INFINITY, sm = 0.f;
    for (int nidx = s0 + k; nidx < s1; nidx += 8) {
        float v = A[(size_t)nidx * 32 + c];
        mx = fmaxf(mx, v);
        sm += v;
    }
    __shared__ float smx[8][32], ssm[8][32];
    smx[k][c] = mx;
    ssm[k][c] = sm;
    __syncthreads();
    if (threadIdx.x < 32) {
        float M = smx[0][c], S = ssm[0][c];
        #pragma unroll
        for (int kk = 1; kk < 8; ++kk) {
            M = fmaxf(M, smx[kk][c]);
            S += ssm[kk][c];
        }
        int cnt = s1 - s0;
        pooled[g * 64 + c] = M;
        pooled[g * 64 + 32 + c] = S / fmaxf((float)cnt, 1.0f);
    }
}

// --- row log_softmax over 64 values -------------------------------------------
__global__ __launch_bounds__(64) void k_lsm(const float* __restrict__ pooled,
                                            float* __restrict__ out) {
    int g = blockIdx.x;
    int l = threadIdx.x;
    float v = pooled[g * 64 + l];
    float m = v;
    #pragma unroll
    for (int o = 32; o > 0; o >>= 1) m = fmaxf(m, __shfl_xor(m, o, 64));
    float e = __expf(v - m);
    float s = e;
    #pragma unroll
    for (int o = 32; o > 0; o >>= 1) s += __shfl_xor(s, o, 64);
    out[g * 64 + l] = v - m - __logf(s);
}

// ---------------------------------------------------------------------------
extern "C" void kernel_launch(void* const* d_in, const int* in_sizes, int n_in,
                              void* d_out, int out_size, void* d_ws, size_t ws_size,
                              hipStream_t stream) {
    const float* x  = (const float*)d_in[0];
    const float* W0 = (const float*)d_in[1];
    const float* b0 = (const float*)d_in[2];
    const float* W1 = (const float*)d_in[3];
    const float* b1 = (const float*)d_in[4];
    const float* W2 = (const float*)d_in[5];
    const float* b2 = (const float*)d_in[6];
    const int* ei_raw    = (const int*)d_in[7];
    const int* batch_raw = (const int*)d_in[8];

    const int N = in_sizes[0] / 96;
    const int E = in_sizes[7] / 2;
    const int G = out_size / 64;
    const int NBUK = (N + 255) >> 8;          // 256 nodes/bucket, <=512 buckets
    float* out = (float*)d_out;

    char* ws = (char*)d_ws;
    size_t off = 0;
    auto alloc = [&](size_t bytes) -> void* {
        void* p = ws + off;
        off += (bytes + 255) & ~(size_t)255;
        return p;
    };
    __half*   Hp96    = (__half*)alloc((size_t)N * 96 * 2);   // gather table, 192B rows
    __half*   As16    = (__half*)alloc((size_t)N * 96 * 2);   // agg out, fp16 natural
    __half*   Hp32    = (__half*)alloc((size_t)N * 32 * 2);   // layer-2 table, 64B rows
    float*    D32     = (float*)alloc((size_t)N * 32 * 4);    // layer-2 agg out
    int*      e32     = (int*)alloc((size_t)2 * E * 4);
    int*      batch32 = (int*)alloc((size_t)N * 4);
    float*    dinv    = (float*)alloc((size_t)N * 4);
    int*      rowptr  = (int*)alloc((size_t)(N + 1) * 4);
    int*      adj     = (int*)alloc((size_t)E * 4);
    unsigned* ebuk    = (unsigned*)alloc((size_t)E * 4);      // bucket-sorted packed edges
    int*      bcnt    = (int*)alloc(512 * 4);
    int*      bstart  = (int*)alloc(513 * 4);
    int*      gcursor = (int*)alloc(512 * 4);
    int*      flag    = (int*)alloc(256);
    int*      gstart  = (int*)alloc((size_t)(G + 1) * 4);
    float*    pooled  = (float*)alloc((size_t)G * 64 * 4);
    __half*   WT0     = (__half*)alloc((size_t)96 * 96 * 2);  // W^T fp16
    __half*   WT1     = (__half*)alloc((size_t)96 * 96 * 2);
    __half*   WT2     = (__half*)alloc((size_t)32 * 96 * 2);

    (void)hipMemsetAsync(bcnt, 0, 512 * 4, stream);
    (void)hipMemsetAsync(gcursor, 0, 512 * 4, stream);

    // index dtype normalize
    k_detect<<<1, 256, 0, stream>>>(ei_raw, flag);
    k_convert<<<(2 * E + 255) / 256, 256, 0, stream>>>(ei_raw, e32, flag, 2 * E);
    k_convert<<<(N + 255) / 256, 256, 0, stream>>>(batch_raw, batch32, flag, N);

    // weight transpose+convert (tiny)
    k_wt<<<(96 * 96 + 255) / 256, 256, 0, stream>>>(W0, WT0, 96);
    k_wt<<<(96 * 96 + 255) / 256, 256, 0, stream>>>(W1, WT1, 96);
    k_wt<<<(32 * 96 + 255) / 256, 256, 0, stream>>>(W2, WT2, 32);

    // CSR via bucket sort
    const int P2B = (E + 8191) / 8192;
    k_p1hist<<<P2B, 512, 0, stream>>>(e32 + E, bcnt, E, NBUK);
    k_bscan<<<1, 512, 0, stream>>>(bcnt, bstart, NBUK, E);
    k_p2scatter<<<P2B, 512, 0, stream>>>(e32, bstart, gcursor, ebuk, E, NBUK);
    k_p3sort<<<NBUK, 256, 0, stream>>>(ebuk, bstart, adj, rowptr, dinv, N, E);
    k_gstart<<<1, 256, 0, stream>>>(batch32, gstart, N, G);

    const int GB = (N + 63) / 64;
    const int AB = (N + 3) / 4;   // 4 nodes per agg block

    // layer 0: A = x fp32
    k_gemm_mfma<96, false><<<GB, 256, 0, stream>>>(x, (const __half*)nullptr, WT0, dinv, Hp96, N);
    k_agg96<true><<<AB, 256, 0, stream>>>(Hp96, dinv, rowptr, adj, b0, As16, N);
    // layer 1: A = As16 fp16
    k_gemm_mfma<96, true><<<GB, 256, 0, stream>>>((const float*)nullptr, As16, WT1, dinv, Hp96, N);
    k_agg96<true><<<AB, 256, 0, stream>>>(Hp96, dinv, rowptr, adj, b1, As16, N);
    // layer 2: A = As16 fp16
    k_gemm_mfma<32, true><<<GB, 256, 0, stream>>>((const float*)nullptr, As16, WT2, dinv, Hp32, N);
    k_agg32<<<AB, 256, 0, stream>>>(Hp32, dinv, rowptr, adj, b2, D32, N);

    // pooling + log_softmax
    k_pool<<<G, 256, 0, stream>>>(D32, gstart, pooled);
    k_lsm<<<G, 64, 0, stream>>>(pooled, out);
}

// Round 12
// 263.157 us; speedup vs baseline: 1.1190x; 1.1190x over previous
//
#include <hip/hip_runtime.h>
#include <hip/hip_fp16.h>
#include <math.h>

// ---------------------------------------------------------------------------
// GCN: 3x (MFMA-fp16 GEMM -> sym-normalized neighbor aggregate) with SiLU,
// then per-graph max+mean pool and log_softmax.
// CSR build = 2-pass bucket sort (round-6 structure).
// Round 12: round-10 structure + unpadded 192B gather tables (round-11's
// validated FETCH win), with ALL nontemporal hints removed (round-11's
// regression source: NT stores evicted data the next kernel re-reads).
// ---------------------------------------------------------------------------

typedef _Float16 f16x8 __attribute__((ext_vector_type(8)));
typedef _Float16 f16x4 __attribute__((ext_vector_type(4)));
typedef float f32x4 __attribute__((ext_vector_type(4)));

static __device__ __forceinline__ float silu_f(float v) {
    return v / (1.0f + __expf(-v));
}

// --- int64-vs-int32 input detection -----------------------------------------
__global__ __launch_bounds__(256) void k_detect(const int* __restrict__ raw,
                                                int* __restrict__ flag) {
    __shared__ int anynz;
    if (threadIdx.x == 0) anynz = 0;
    __syncthreads();
    if (raw[2 * threadIdx.x + 1] != 0) anynz = 1;  // benign race, same value
    __syncthreads();
    if (threadIdx.x == 0) *flag = (anynz ? 0 : 1); // 1 => int64
}

__global__ __launch_bounds__(256) void k_convert(const int* __restrict__ raw,
                                                 int* __restrict__ out,
                                                 const int* __restrict__ flag,
                                                 int count) {
    int i = blockIdx.x * 256 + threadIdx.x;
    if (i < count) out[i] = flag[0] ? raw[2 * i] : raw[i];
}

// --- CSR pass 1: bucket histogram (bucket = dst>>8, <=512 buckets) -----------
__global__ __launch_bounds__(512) void k_p1hist(const int* __restrict__ dst,
                                                int* __restrict__ bcnt,
                                                int E, int nbuk) {
    __shared__ int hs[512];
    const int t = threadIdx.x;
    hs[t] = 0;
    __syncthreads();
    const int base = blockIdx.x * 8192;
    const int lim = min(base + 8192, E);
    for (int j = base + t; j < lim; j += 512)
        atomicAdd(&hs[dst[j] >> 8], 1);
    __syncthreads();
    if (t < nbuk && hs[t]) atomicAdd(&bcnt[t], hs[t]);
}

// --- CSR pass 1b: exclusive scan of bucket counts -> bstart ------------------
__global__ __launch_bounds__(512) void k_bscan(const int* __restrict__ bcnt,
                                               int* __restrict__ bstart,
                                               int nbuk, int E) {
    __shared__ int lds[512];
    int t = threadIdx.x;
    int v = (t < nbuk) ? bcnt[t] : 0;
    lds[t] = v;
    __syncthreads();
    for (int off = 1; off < 512; off <<= 1) {
        int y = (t >= off) ? lds[t - off] : 0;
        __syncthreads();
        lds[t] += y;
        __syncthreads();
    }
    if (t < nbuk) bstart[t] = lds[t] - v;
    if (t == 0) bstart[nbuk] = E;
}

// --- CSR pass 2: bucket scatter, block-staged ---------------------------------
__global__ __launch_bounds__(512) void k_p2scatter(const int* __restrict__ e32,
                                                   const int* __restrict__ bstart,
                                                   int* __restrict__ gcursor,
                                                   unsigned* __restrict__ ebuk,
                                                   int E, int nbuk) {
    __shared__ int hs[512], sc[512], lexcl[512], pl[512], gb[512];
    __shared__ unsigned stg[8192];
    __shared__ unsigned short stb[8192];
    const int t = threadIdx.x;
    const int base = blockIdx.x * 8192;
    const int len = min(8192, E - base);
    const int* __restrict__ dstp = e32 + E;

    hs[t] = 0;
    __syncthreads();
    for (int j = t; j < len; j += 512)
        atomicAdd(&hs[dstp[base + j] >> 8], 1);
    __syncthreads();

    int cv = (t < nbuk) ? hs[t] : 0;
    sc[t] = cv;
    __syncthreads();
    for (int off = 1; off < 512; off <<= 1) {
        int y = (t >= off) ? sc[t - off] : 0;
        __syncthreads();
        sc[t] += y;
        __syncthreads();
    }
    int ex = sc[t] - cv;
    if (t < nbuk) {
        lexcl[t] = ex;
        pl[t] = ex;
        gb[t] = cv ? atomicAdd(&gcursor[t], cv) : 0;
    }
    __syncthreads();

    for (int j = t; j < len; j += 512) {
        int d = dstp[base + j];
        int s = e32[base + j];
        int b = d >> 8;
        int slot = atomicAdd(&pl[b], 1);
        stg[slot] = ((unsigned)s << 8) | (unsigned)(d & 255);
        stb[slot] = (unsigned short)b;
    }
    __syncthreads();

    for (int s2 = t; s2 < len; s2 += 512) {
        int b = stb[s2];
        int gpos = bstart[b] + gb[b] + (s2 - lexcl[b]);
        ebuk[gpos] = stg[s2];
    }
}

// --- CSR pass 3: per-bucket counting sort -> adj, rowptr, dinv ----------------
__global__ __launch_bounds__(256) void k_p3sort(const unsigned* __restrict__ ebuk,
                                                const int* __restrict__ bstart,
                                                int* __restrict__ adj,
                                                int* __restrict__ rowptr,
                                                float* __restrict__ dinv,
                                                int n, int E) {
    const int b = blockIdx.x;
    const int t = threadIdx.x;
    const int s0 = bstart[b], s1 = bstart[b + 1];
    __shared__ int cs[256], pl[256];
    cs[t] = 0;
    __syncthreads();
    for (int j = s0 + t; j < s1; j += 256)
        atomicAdd(&cs[ebuk[j] & 255], 1);
    __syncthreads();
    int cv = cs[t];
    pl[t] = cv;
    __syncthreads();
    for (int off = 1; off < 256; off <<= 1) {
        int y = (t >= off) ? pl[t - off] : 0;
        __syncthreads();
        pl[t] += y;
        __syncthreads();
    }
    int ex = pl[t] - cv;
    __syncthreads();
    pl[t] = ex;
    int node = (b << 8) + t;
    if (node < n) {
        rowptr[node] = s0 + ex;
        dinv[node] = rsqrtf((float)cv + 1.0f);  // +1 self loop
    }
    if (b == 0 && t == 0) rowptr[n] = E;
    __syncthreads();
    for (int j = s0 + t; j < s1; j += 256) {
        unsigned p = ebuk[j];
        int slot = atomicAdd(&pl[p & 255], 1);
        adj[s0 + slot] = (int)(p >> 8);
    }
}

// --- per-graph boundaries (batch is sorted) -----------------------------------
__global__ __launch_bounds__(256) void k_gstart(const int* __restrict__ batch,
                                                int* __restrict__ gstart,
                                                int n, int G) {
    int t = threadIdx.x;
    if (t > G) return;
    int lo = 0, hi = n;
    while (lo < hi) {
        int mid = (lo + hi) >> 1;
        if (batch[mid] < t) lo = mid + 1; else hi = mid;
    }
    gstart[t] = lo;
}

// --- W transpose + fp16 convert: WT[n][k] = fp16(W[k][n]) ---------------------
__global__ __launch_bounds__(256) void k_wt(const float* __restrict__ W,
                                            __half* __restrict__ WT, int fout) {
    int idx = blockIdx.x * 256 + threadIdx.x;
    if (idx < fout * 96) {
        int nn = idx / 96, kk = idx - nn * 96;
        WT[idx] = __float2half(W[kk * fout + nn]);
    }
}

// --- MFMA GEMM: H[r,:] = fp16( dinv[r] * (A[r,:96] @ W) ), LDS-free ----------
// A: fp32 natural (AHALF=0, layer 0 input x) or fp16 natural 96-stride
// (AHALF=1, agg output). Output: fp16 natural FOUT-stride.
// A and B share identical per-lane k-addressing -> the hardware k->slot map
// cancels (dot products are k-permutation invariant).
template <int FOUT, bool AHALF>
__global__ __launch_bounds__(256) void k_gemm_mfma(const float* __restrict__ Xf,
                                                   const __half* __restrict__ Xh,
                                                   const __half* __restrict__ WT,
                                                   const float* __restrict__ dinv,
                                                   __half* __restrict__ H, int n) {
    const int l = threadIdx.x & 63;
    const int w = threadIdx.x >> 6;
    const int row0 = blockIdx.x * 64 + w * 16;
    const int lr = l & 15, lg = l >> 4;
    constexpr int NT = FOUT / 16;

    f16x8 bfrag[NT][3];
    #pragma unroll
    for (int t = 0; t < NT; ++t)
        #pragma unroll
        for (int kk = 0; kk < 3; ++kk)
            bfrag[t][kk] = *(const f16x8*)&WT[(t * 16 + lr) * 96 + kk * 32 + lg * 8];

    f32x4 acc[NT];
    #pragma unroll
    for (int t = 0; t < NT; ++t) acc[t] = (f32x4){0.f, 0.f, 0.f, 0.f};

    int arow = row0 + lr;
    int arow_c = arow < n ? arow : n - 1;  // clamp; garbage rows never stored

    #pragma unroll
    for (int kk = 0; kk < 3; ++kk) {
        f16x8 af;
        if (AHALF) {
            af = *(const f16x8*)(Xh + (size_t)arow_c * 96 + kk * 32 + lg * 8);
        } else {
            const float* xr = Xf + (size_t)arow_c * 96;
            float4 u0 = *(const float4*)&xr[kk * 32 + lg * 8];
            float4 u1 = *(const float4*)&xr[kk * 32 + lg * 8 + 4];
            af[0] = (_Float16)u0.x; af[1] = (_Float16)u0.y;
            af[2] = (_Float16)u0.z; af[3] = (_Float16)u0.w;
            af[4] = (_Float16)u1.x; af[5] = (_Float16)u1.y;
            af[6] = (_Float16)u1.z; af[7] = (_Float16)u1.w;
        }
        #pragma unroll
        for (int t = 0; t < NT; ++t)
            acc[t] = __builtin_amdgcn_mfma_f32_16x16x32_f16(af, bfrag[t][kk], acc[t], 0, 0, 0);
    }

    // C/D: col = t*16+lr, row = row0 + lg*4 + i  (m89-verified map)
    #pragma unroll
    for (int i = 0; i < 4; ++i) {
        int r = row0 + lg * 4 + i;
        if (r < n) {
            float dv = dinv[r];
            #pragma unroll
            for (int t = 0; t < NT; ++t)
                H[(size_t)r * FOUT + t * 16 + lr] = __float2half(acc[t][i] * dv);
        }
    }
}

// --- aggregation, F=96, UNPADDED 192B rows ------------------------------------
// One wave per node. Quarter q = l>>4 owns one edge-chain; lane li = l&15:
// li<12 loads octet li (f16x8) of the row; li>=12 clamps to octet li-12
// (same-row broadcast, no extra lines; results discarded). 8 edges/iter =
// 2 gathers/lane; tail masked via the w multiplier (v_fma_mix_f32).
// Output fp16 natural [n][96].
template <bool SILU>
__global__ __launch_bounds__(256) void k_agg96(const __half* __restrict__ Hp,
                                               const float* __restrict__ dinv,
                                               const int* __restrict__ rowptr,
                                               const int* __restrict__ adj,
                                               const float* __restrict__ bias,
                                               __half* __restrict__ OUT, int n) {
    const int l = threadIdx.x & 63;
    const int node = blockIdx.x * 4 + (threadIdx.x >> 6);
    if (node >= n) return;
    const int q = l >> 4;
    const int li = l & 15;
    const int oct = li < 12 ? li : li - 12;   // octet within row (broadcast for pads)
    const float dn = dinv[node];
    const int e0 = rowptr[node], e1 = rowptr[node + 1];
    const f16x8* __restrict__ H8 = (const f16x8*)Hp;  // 12 f16x8 per row

    float acc[8] = {0.f, 0.f, 0.f, 0.f, 0.f, 0.f, 0.f, 0.f};

    // self row (counted once, quarter 0)
    {
        f16x8 v = H8[(size_t)node * 12 + oct];
        float ws = (q == 0) ? 1.f : 0.f;
        #pragma unroll
        for (int i = 0; i < 8; ++i) acc[i] = fmaf((float)v[i], ws, acc[i]);
    }

    for (int e = e0; e < e1; e += 8) {
        int ai = e + (l & 7);
        int v_s = adj[ai < e1 ? ai : e1 - 1];  // coalesced: 8 edge srcs
        #pragma unroll
        for (int j = 0; j < 2; ++j) {
            int c = 4 * j + q;
            int s = __shfl(v_s, c, 64);
            float w = (e + c < e1) ? 1.f : 0.f;
            f16x8 v = H8[(size_t)s * 12 + oct];
            #pragma unroll
            for (int i = 0; i < 8; ++i) acc[i] = fmaf((float)v[i], w, acc[i]);
        }
    }

    // reduce across quarters (li lanes only talk to same-li lanes)
    #pragma unroll
    for (int i = 0; i < 8; ++i) {
        acc[i] += __shfl_xor(acc[i], 16, 64);
        acc[i] += __shfl_xor(acc[i], 32, 64);
    }

    if (l < 12) {  // q==0, li<12: lane li owns features 8li..8li+7
        float4 bv0 = ((const float4*)bias)[2 * l];
        float4 bv1 = ((const float4*)bias)[2 * l + 1];
        float o0 = acc[0] * dn + bv0.x, o1 = acc[1] * dn + bv0.y;
        float o2 = acc[2] * dn + bv0.z, o3 = acc[3] * dn + bv0.w;
        float o4 = acc[4] * dn + bv1.x, o5 = acc[5] * dn + bv1.y;
        float o6 = acc[6] * dn + bv1.z, o7 = acc[7] * dn + bv1.w;
        if (SILU) {
            o0 = silu_f(o0); o1 = silu_f(o1); o2 = silu_f(o2); o3 = silu_f(o3);
            o4 = silu_f(o4); o5 = silu_f(o5); o6 = silu_f(o6); o7 = silu_f(o7);
        }
        f16x8 wv = {(_Float16)o0, (_Float16)o1, (_Float16)o2, (_Float16)o3,
                    (_Float16)o4, (_Float16)o5, (_Float16)o6, (_Float16)o7};
        *(f16x8*)(OUT + (size_t)node * 96 + l * 8) = wv;
    }
}

// --- aggregation, F=32, natural 64B rows --------------------------------------
// 8-lane row groups; lane li loads f16x4 (8B). g = l>>3 owns one edge-chain.
__global__ __launch_bounds__(256) void k_agg32(const __half* __restrict__ Hp,
                                               const float* __restrict__ dinv,
                                               const int* __restrict__ rowptr,
                                               const int* __restrict__ adj,
                                               const float* __restrict__ bias,
                                               float* __restrict__ OUT, int n) {
    const int l = threadIdx.x & 63;
    const int node = blockIdx.x * 4 + (threadIdx.x >> 6);
    if (node >= n) return;
    const int g = l >> 3;
    const int li = l & 7;
    const float dn = dinv[node];
    const int e0 = rowptr[node], e1 = rowptr[node + 1];
    const f16x4* __restrict__ H4 = (const f16x4*)Hp;  // 8 f16x4 per row

    float acc[4] = {0.f, 0.f, 0.f, 0.f};

    {
        f16x4 v = H4[(size_t)node * 8 + li];
        float ws = (g == 0) ? 1.f : 0.f;
        #pragma unroll
        for (int i = 0; i < 4; ++i) acc[i] = fmaf((float)v[i], ws, acc[i]);
    }

    for (int e = e0; e < e1; e += 8) {
        int ai = e + (l & 7);
        int v_s = adj[ai < e1 ? ai : e1 - 1];
        int src = __shfl(v_s, g, 64);
        float w = (e + g < e1) ? 1.f : 0.f;
        f16x4 v = H4[(size_t)src * 8 + li];
        #pragma unroll
        for (int i = 0; i < 4; ++i) acc[i] = fmaf((float)v[i], w, acc[i]);
    }

    #pragma unroll
    for (int i = 0; i < 4; ++i) {
        acc[i] += __shfl_xor(acc[i], 8, 64);
        acc[i] += __shfl_xor(acc[i], 16, 64);
        acc[i] += __shfl_xor(acc[i], 32, 64);
    }

    if (l < 8) {  // lane li owns features 4li..4li+3
        float4 bv = ((const float4*)bias)[l];
        float4 o = make_float4(acc[0] * dn + bv.x, acc[1] * dn + bv.y,
                               acc[2] * dn + bv.z, acc[3] * dn + bv.w);
        ((float4*)(OUT + (size_t)node * 32))[l] = o;
    }
}

// --- per-graph max+mean pool (block per graph) --------------------------------
__global__ __launch_bounds__(256) void k_pool(const float* __restrict__ A,
                                              const int* __restrict__ gstart,
                                              float* __restrict__ pooled) {
    int g = blockIdx.x;
    int s0 = gstart[g], s1 = gstart[g + 1];
    int c = threadIdx.x & 31, k = threadIdx.x >> 5;
    float mx = -INFINITY, sm = 0.f;
    for (int nidx = s0 + k; nidx < s1; nidx += 8) {
        float v = A[(size_t)nidx * 32 + c];
        mx = fmaxf(mx, v);
        sm += v;
    }
    __shared__ float smx[8][32], ssm[8][32];
    smx[k][c] = mx;
    ssm[k][c] = sm;
    __syncthreads();
    if (threadIdx.x < 32) {
        float M = smx[0][c], S = ssm[0][c];
        #pragma unroll
        for (int kk = 1; kk < 8; ++kk) {
            M = fmaxf(M, smx[kk][c]);
            S += ssm[kk][c];
        }
        int cnt = s1 - s0;
        pooled[g * 64 + c] = M;
        pooled[g * 64 + 32 + c] = S / fmaxf((float)cnt, 1.0f);
    }
}

// --- row log_softmax over 64 values -------------------------------------------
__global__ __launch_bounds__(64) void k_lsm(const float* __restrict__ pooled,
                                            float* __restrict__ out) {
    int g = blockIdx.x;
    int l = threadIdx.x;
    float v = pooled[g * 64 + l];
    float m = v;
    #pragma unroll
    for (int o = 32; o > 0; o >>= 1) m = fmaxf(m, __shfl_xor(m, o, 64));
    float e = __expf(v - m);
    float s = e;
    #pragma unroll
    for (int o = 32; o > 0; o >>= 1) s += __shfl_xor(s, o, 64);
    out[g * 64 + l] = v - m - __logf(s);
}

// ---------------------------------------------------------------------------
extern "C" void kernel_launch(void* const* d_in, const int* in_sizes, int n_in,
                              void* d_out, int out_size, void* d_ws, size_t ws_size,
                              hipStream_t stream) {
    const float* x  = (const float*)d_in[0];
    const float* W0 = (const float*)d_in[1];
    const float* b0 = (const float*)d_in[2];
    const float* W1 = (const float*)d_in[3];
    const float* b1 = (const float*)d_in[4];
    const float* W2 = (const float*)d_in[5];
    const float* b2 = (const float*)d_in[6];
    const int* ei_raw    = (const int*)d_in[7];
    const int* batch_raw = (const int*)d_in[8];

    const int N = in_sizes[0] / 96;
    const int E = in_sizes[7] / 2;
    const int G = out_size / 64;
    const int NBUK = (N + 255) >> 8;          // 256 nodes/bucket, <=512 buckets
    float* out = (float*)d_out;

    char* ws = (char*)d_ws;
    size_t off = 0;
    auto alloc = [&](size_t bytes) -> void* {
        void* p = ws + off;
        off += (bytes + 255) & ~(size_t)255;
        return p;
    };
    __half*   Hp96    = (__half*)alloc((size_t)N * 96 * 2);   // gather table, 192B rows
    __half*   As16    = (__half*)alloc((size_t)N * 96 * 2);   // agg out, fp16 natural
    __half*   Hp32    = (__half*)alloc((size_t)N * 32 * 2);   // layer-2 table, 64B rows
    float*    D32     = (float*)alloc((size_t)N * 32 * 4);    // layer-2 agg out
    int*      e32     = (int*)alloc((size_t)2 * E * 4);
    int*      batch32 = (int*)alloc((size_t)N * 4);
    float*    dinv    = (float*)alloc((size_t)N * 4);
    int*      rowptr  = (int*)alloc((size_t)(N + 1) * 4);
    int*      adj     = (int*)alloc((size_t)E * 4);
    unsigned* ebuk    = (unsigned*)alloc((size_t)E * 4);      // bucket-sorted packed edges
    int*      bcnt    = (int*)alloc(512 * 4);
    int*      bstart  = (int*)alloc(513 * 4);
    int*      gcursor = (int*)alloc(512 * 4);
    int*      flag    = (int*)alloc(256);
    int*      gstart  = (int*)alloc((size_t)(G + 1) * 4);
    float*    pooled  = (float*)alloc((size_t)G * 64 * 4);
    __half*   WT0     = (__half*)alloc((size_t)96 * 96 * 2);  // W^T fp16
    __half*   WT1     = (__half*)alloc((size_t)96 * 96 * 2);
    __half*   WT2     = (__half*)alloc((size_t)32 * 96 * 2);

    (void)hipMemsetAsync(bcnt, 0, 512 * 4, stream);
    (void)hipMemsetAsync(gcursor, 0, 512 * 4, stream);

    // index dtype normalize
    k_detect<<<1, 256, 0, stream>>>(ei_raw, flag);
    k_convert<<<(2 * E + 255) / 256, 256, 0, stream>>>(ei_raw, e32, flag, 2 * E);
    k_convert<<<(N + 255) / 256, 256, 0, stream>>>(batch_raw, batch32, flag, N);

    // weight transpose+convert (tiny)
    k_wt<<<(96 * 96 + 255) / 256, 256, 0, stream>>>(W0, WT0, 96);
    k_wt<<<(96 * 96 + 255) / 256, 256, 0, stream>>>(W1, WT1, 96);
    k_wt<<<(32 * 96 + 255) / 256, 256, 0, stream>>>(W2, WT2, 32);

    // CSR via bucket sort
    const int P2B = (E + 8191) / 8192;
    k_p1hist<<<P2B, 512, 0, stream>>>(e32 + E, bcnt, E, NBUK);
    k_bscan<<<1, 512, 0, stream>>>(bcnt, bstart, NBUK, E);
    k_p2scatter<<<P2B, 512, 0, stream>>>(e32, bstart, gcursor, ebuk, E, NBUK);
    k_p3sort<<<NBUK, 256, 0, stream>>>(ebuk, bstart, adj, rowptr, dinv, N, E);
    k_gstart<<<1, 256, 0, stream>>>(batch32, gstart, N, G);

    const int GB = (N + 63) / 64;
    const int AB = (N + 3) / 4;   // 4 nodes per agg block

    // layer 0: A = x fp32
    k_gemm_mfma<96, false><<<GB, 256, 0, stream>>>(x, (const __half*)nullptr, WT0, dinv, Hp96, N);
    k_agg96<true><<<AB, 256, 0, stream>>>(Hp96, dinv, rowptr, adj, b0, As16, N);
    // layer 1: A = As16 fp16
    k_gemm_mfma<96, true><<<GB, 256, 0, stream>>>((const float*)nullptr, As16, WT1, dinv, Hp96, N);
    k_agg96<true><<<AB, 256, 0, stream>>>(Hp96, dinv, rowptr, adj, b1, As16, N);
    // layer 2: A = As16 fp16
    k_gemm_mfma<32, true><<<GB, 256, 0, stream>>>((const float*)nullptr, As16, WT2, dinv, Hp32, N);
    k_agg32<<<AB, 256, 0, stream>>>(Hp32, dinv, rowptr, adj, b2, D32, N);

    // pooling + log_softmax
    k_pool<<<G, 256, 0, stream>>>(D32, gstart, pooled);
    k_lsm<<<G, 64, 0, stream>>>(pooled, out);
}

// Round 13
// 251.579 us; speedup vs baseline: 1.1705x; 1.0460x over previous
//
#include <hip/hip_runtime.h>
#include <hip/hip_fp16.h>
#include <math.h>

// ---------------------------------------------------------------------------
// GCN: 3x (MFMA-fp16 GEMM -> sym-normalized neighbor aggregate) with SiLU,
// then per-graph max+mean pool and log_softmax.
// Round 13: round-12 structure (unpadded 192B tables, no NT hints) plus:
//   - agg loops software-pipelined: next adj vector prefetched during FMAs,
//     both chain gathers issued before FMAs (agg is latency-bound, not BW).
//   - int64->int32 conversion folded into p1hist/p2scatter/gstart (no e32/
//     batch32 buffers, -3 dispatches, -12.8MB pass-through traffic).
//   - 3x k_wt fused into one; pool+lsm fused into one.
// ---------------------------------------------------------------------------

typedef _Float16 f16x8 __attribute__((ext_vector_type(8)));
typedef _Float16 f16x4 __attribute__((ext_vector_type(4)));
typedef float f32x4 __attribute__((ext_vector_type(4)));

static __device__ __forceinline__ float silu_f(float v) {
    return v / (1.0f + __expf(-v));
}

// raw index read honoring int64 (flagged) or int32 layout
static __device__ __forceinline__ int raw_at(const int* __restrict__ raw,
                                             int idx, int f64) {
    return raw[f64 ? 2 * idx : idx];
}

// --- int64-vs-int32 input detection -----------------------------------------
__global__ __launch_bounds__(256) void k_detect(const int* __restrict__ raw,
                                                int* __restrict__ flag) {
    __shared__ int anynz;
    if (threadIdx.x == 0) anynz = 0;
    __syncthreads();
    if (raw[2 * threadIdx.x + 1] != 0) anynz = 1;  // benign race, same value
    __syncthreads();
    if (threadIdx.x == 0) *flag = (anynz ? 0 : 1); // 1 => int64
}

// --- CSR pass 1: bucket histogram (bucket = dst>>8, <=512 buckets) -----------
__global__ __launch_bounds__(512) void k_p1hist(const int* __restrict__ eraw,
                                                const int* __restrict__ flag,
                                                int* __restrict__ bcnt,
                                                int E, int nbuk) {
    __shared__ int hs[512];
    const int t = threadIdx.x;
    const int f64 = flag[0];
    hs[t] = 0;
    __syncthreads();
    const int base = blockIdx.x * 8192;
    const int lim = min(base + 8192, E);
    for (int j = base + t; j < lim; j += 512)
        atomicAdd(&hs[raw_at(eraw, E + j, f64) >> 8], 1);
    __syncthreads();
    if (t < nbuk && hs[t]) atomicAdd(&bcnt[t], hs[t]);
}

// --- CSR pass 1b: exclusive scan of bucket counts -> bstart ------------------
__global__ __launch_bounds__(512) void k_bscan(const int* __restrict__ bcnt,
                                               int* __restrict__ bstart,
                                               int nbuk, int E) {
    __shared__ int lds[512];
    int t = threadIdx.x;
    int v = (t < nbuk) ? bcnt[t] : 0;
    lds[t] = v;
    __syncthreads();
    for (int off = 1; off < 512; off <<= 1) {
        int y = (t >= off) ? lds[t - off] : 0;
        __syncthreads();
        lds[t] += y;
        __syncthreads();
    }
    if (t < nbuk) bstart[t] = lds[t] - v;
    if (t == 0) bstart[nbuk] = E;
}

// --- CSR pass 2: bucket scatter, block-staged ---------------------------------
__global__ __launch_bounds__(512) void k_p2scatter(const int* __restrict__ eraw,
                                                   const int* __restrict__ flag,
                                                   const int* __restrict__ bstart,
                                                   int* __restrict__ gcursor,
                                                   unsigned* __restrict__ ebuk,
                                                   int E, int nbuk) {
    __shared__ int hs[512], sc[512], lexcl[512], pl[512], gb[512];
    __shared__ unsigned stg[8192];
    __shared__ unsigned short stb[8192];
    const int t = threadIdx.x;
    const int f64 = flag[0];
    const int base = blockIdx.x * 8192;
    const int len = min(8192, E - base);

    hs[t] = 0;
    __syncthreads();
    for (int j = t; j < len; j += 512)
        atomicAdd(&hs[raw_at(eraw, E + base + j, f64) >> 8], 1);
    __syncthreads();

    int cv = (t < nbuk) ? hs[t] : 0;
    sc[t] = cv;
    __syncthreads();
    for (int off = 1; off < 512; off <<= 1) {
        int y = (t >= off) ? sc[t - off] : 0;
        __syncthreads();
        sc[t] += y;
        __syncthreads();
    }
    int ex = sc[t] - cv;
    if (t < nbuk) {
        lexcl[t] = ex;
        pl[t] = ex;
        gb[t] = cv ? atomicAdd(&gcursor[t], cv) : 0;
    }
    __syncthreads();

    for (int j = t; j < len; j += 512) {
        int d = raw_at(eraw, E + base + j, f64);
        int s = raw_at(eraw, base + j, f64);
        int b = d >> 8;
        int slot = atomicAdd(&pl[b], 1);
        stg[slot] = ((unsigned)s << 8) | (unsigned)(d & 255);
        stb[slot] = (unsigned short)b;
    }
    __syncthreads();

    for (int s2 = t; s2 < len; s2 += 512) {
        int b = stb[s2];
        int gpos = bstart[b] + gb[b] + (s2 - lexcl[b]);
        ebuk[gpos] = stg[s2];
    }
}

// --- CSR pass 3: per-bucket counting sort -> adj, rowptr, dinv ----------------
__global__ __launch_bounds__(256) void k_p3sort(const unsigned* __restrict__ ebuk,
                                                const int* __restrict__ bstart,
                                                int* __restrict__ adj,
                                                int* __restrict__ rowptr,
                                                float* __restrict__ dinv,
                                                int n, int E) {
    const int b = blockIdx.x;
    const int t = threadIdx.x;
    const int s0 = bstart[b], s1 = bstart[b + 1];
    __shared__ int cs[256], pl[256];
    cs[t] = 0;
    __syncthreads();
    for (int j = s0 + t; j < s1; j += 256)
        atomicAdd(&cs[ebuk[j] & 255], 1);
    __syncthreads();
    int cv = cs[t];
    pl[t] = cv;
    __syncthreads();
    for (int off = 1; off < 256; off <<= 1) {
        int y = (t >= off) ? pl[t - off] : 0;
        __syncthreads();
        pl[t] += y;
        __syncthreads();
    }
    int ex = pl[t] - cv;
    __syncthreads();
    pl[t] = ex;
    int node = (b << 8) + t;
    if (node < n) {
        rowptr[node] = s0 + ex;
        dinv[node] = rsqrtf((float)cv + 1.0f);  // +1 self loop
    }
    if (b == 0 && t == 0) rowptr[n] = E;
    __syncthreads();
    for (int j = s0 + t; j < s1; j += 256) {
        unsigned p = ebuk[j];
        int slot = atomicAdd(&pl[p & 255], 1);
        adj[s0 + slot] = (int)(p >> 8);
    }
}

// --- per-graph boundaries (batch is sorted; raw int64/int32) -------------------
__global__ __launch_bounds__(256) void k_gstart(const int* __restrict__ braw,
                                                const int* __restrict__ flag,
                                                int* __restrict__ gstart,
                                                int n, int G) {
    int t = threadIdx.x;
    if (t > G) return;
    const int f64 = flag[0];
    int lo = 0, hi = n;
    while (lo < hi) {
        int mid = (lo + hi) >> 1;
        if (raw_at(braw, mid, f64) < t) lo = mid + 1; else hi = mid;
    }
    gstart[t] = lo;
}

// --- fused W transpose + fp16 convert for all 3 weights ------------------------
// WT arena: [0,9216) = W0^T (96x96), [9216,18432) = W1^T, [18432,21504) = W2^T.
__global__ __launch_bounds__(256) void k_wt3(const float* __restrict__ W0,
                                             const float* __restrict__ W1,
                                             const float* __restrict__ W2,
                                             __half* __restrict__ WT) {
    int idx = blockIdx.x * 256 + threadIdx.x;
    if (idx >= 21504) return;
    const float* W;
    int fout, loc;
    if (idx < 9216)       { W = W0; fout = 96; loc = idx; }
    else if (idx < 18432) { W = W1; fout = 96; loc = idx - 9216; }
    else                  { W = W2; fout = 32; loc = idx - 18432; }
    int nn = loc / 96, kk = loc - nn * 96;
    WT[idx] = __float2half(W[kk * fout + nn]);
}

// --- MFMA GEMM: H[r,:] = fp16( dinv[r] * (A[r,:96] @ W) ), LDS-free ----------
template <int FOUT, bool AHALF>
__global__ __launch_bounds__(256) void k_gemm_mfma(const float* __restrict__ Xf,
                                                   const __half* __restrict__ Xh,
                                                   const __half* __restrict__ WT,
                                                   const float* __restrict__ dinv,
                                                   __half* __restrict__ H, int n) {
    const int l = threadIdx.x & 63;
    const int w = threadIdx.x >> 6;
    const int row0 = blockIdx.x * 64 + w * 16;
    const int lr = l & 15, lg = l >> 4;
    constexpr int NT = FOUT / 16;

    f16x8 bfrag[NT][3];
    #pragma unroll
    for (int t = 0; t < NT; ++t)
        #pragma unroll
        for (int kk = 0; kk < 3; ++kk)
            bfrag[t][kk] = *(const f16x8*)&WT[(t * 16 + lr) * 96 + kk * 32 + lg * 8];

    f32x4 acc[NT];
    #pragma unroll
    for (int t = 0; t < NT; ++t) acc[t] = (f32x4){0.f, 0.f, 0.f, 0.f};

    int arow = row0 + lr;
    int arow_c = arow < n ? arow : n - 1;  // clamp; garbage rows never stored

    #pragma unroll
    for (int kk = 0; kk < 3; ++kk) {
        f16x8 af;
        if (AHALF) {
            af = *(const f16x8*)(Xh + (size_t)arow_c * 96 + kk * 32 + lg * 8);
        } else {
            const float* xr = Xf + (size_t)arow_c * 96;
            float4 u0 = *(const float4*)&xr[kk * 32 + lg * 8];
            float4 u1 = *(const float4*)&xr[kk * 32 + lg * 8 + 4];
            af[0] = (_Float16)u0.x; af[1] = (_Float16)u0.y;
            af[2] = (_Float16)u0.z; af[3] = (_Float16)u0.w;
            af[4] = (_Float16)u1.x; af[5] = (_Float16)u1.y;
            af[6] = (_Float16)u1.z; af[7] = (_Float16)u1.w;
        }
        #pragma unroll
        for (int t = 0; t < NT; ++t)
            acc[t] = __builtin_amdgcn_mfma_f32_16x16x32_f16(af, bfrag[t][kk], acc[t], 0, 0, 0);
    }

    // C/D: col = t*16+lr, row = row0 + lg*4 + i  (m89-verified map)
    #pragma unroll
    for (int i = 0; i < 4; ++i) {
        int r = row0 + lg * 4 + i;
        if (r < n) {
            float dv = dinv[r];
            #pragma unroll
            for (int t = 0; t < NT; ++t)
                H[(size_t)r * FOUT + t * 16 + lr] = __float2half(acc[t][i] * dv);
        }
    }
}

// --- aggregation, F=96, UNPADDED 192B rows, software-pipelined -----------------
// One wave per node. Quarter q = l>>4 owns 2 edge-chains; lane li = l&15:
// li<12 loads octet li (f16x8); li>=12 clamps to octet li-12 (same-row
// broadcast, discarded). 8 edges/iter; next iteration's adj vector is
// prefetched during this iteration's FMAs; both chain gathers issue before
// any FMA. Tail masked via w multiplier (v_fma_mix_f32).
template <bool SILU>
__global__ __launch_bounds__(256) void k_agg96(const __half* __restrict__ Hp,
                                               const float* __restrict__ dinv,
                                               const int* __restrict__ rowptr,
                                               const int* __restrict__ adj,
                                               const float* __restrict__ bias,
                                               __half* __restrict__ OUT, int n) {
    const int l = threadIdx.x & 63;
    const int node = blockIdx.x * 4 + (threadIdx.x >> 6);
    if (node >= n) return;
    const int q = l >> 4;
    const int li = l & 15;
    const int oct = li < 12 ? li : li - 12;   // octet within row (broadcast for pads)
    const float dn = dinv[node];
    const int e0 = rowptr[node], e1 = rowptr[node + 1];
    const f16x8* __restrict__ H8 = (const f16x8*)Hp;  // 12 f16x8 per row

    float acc[8] = {0.f, 0.f, 0.f, 0.f, 0.f, 0.f, 0.f, 0.f};

    // prologue: first adj vector (uniform guard; deg=0 safe)
    int vs = 0;
    if (e0 < e1) vs = adj[min(e0 + (l & 7), e1 - 1)];

    // self row (counted once, quarter 0) — load overlaps first adj fetch
    {
        f16x8 v = H8[(size_t)node * 12 + oct];
        float ws = (q == 0) ? 1.f : 0.f;
        #pragma unroll
        for (int i = 0; i < 8; ++i) acc[i] = fmaf((float)v[i], ws, acc[i]);
    }

    for (int e = e0; e < e1; e += 8) {
        int vs_next = vs;
        if (e + 8 < e1) vs_next = adj[min(e + 8 + (l & 7), e1 - 1)];  // prefetch
        int s0 = __shfl(vs, q, 64);
        int s1 = __shfl(vs, 4 + q, 64);
        float w0 = (e + q < e1) ? 1.f : 0.f;
        float w1 = (e + 4 + q < e1) ? 1.f : 0.f;
        f16x8 v0 = H8[(size_t)s0 * 12 + oct];   // both gathers in flight
        f16x8 v1 = H8[(size_t)s1 * 12 + oct];
        #pragma unroll
        for (int i = 0; i < 8; ++i) acc[i] = fmaf((float)v0[i], w0, acc[i]);
        #pragma unroll
        for (int i = 0; i < 8; ++i) acc[i] = fmaf((float)v1[i], w1, acc[i]);
        vs = vs_next;
    }

    // reduce across quarters (li lanes only talk to same-li lanes)
    #pragma unroll
    for (int i = 0; i < 8; ++i) {
        acc[i] += __shfl_xor(acc[i], 16, 64);
        acc[i] += __shfl_xor(acc[i], 32, 64);
    }

    if (l < 12) {  // q==0, li<12: lane li owns features 8li..8li+7
        float4 bv0 = ((const float4*)bias)[2 * l];
        float4 bv1 = ((const float4*)bias)[2 * l + 1];
        float o0 = acc[0] * dn + bv0.x, o1 = acc[1] * dn + bv0.y;
        float o2 = acc[2] * dn + bv0.z, o3 = acc[3] * dn + bv0.w;
        float o4 = acc[4] * dn + bv1.x, o5 = acc[5] * dn + bv1.y;
        float o6 = acc[6] * dn + bv1.z, o7 = acc[7] * dn + bv1.w;
        if (SILU) {
            o0 = silu_f(o0); o1 = silu_f(o1); o2 = silu_f(o2); o3 = silu_f(o3);
            o4 = silu_f(o4); o5 = silu_f(o5); o6 = silu_f(o6); o7 = silu_f(o7);
        }
        f16x8 wv = {(_Float16)o0, (_Float16)o1, (_Float16)o2, (_Float16)o3,
                    (_Float16)o4, (_Float16)o5, (_Float16)o6, (_Float16)o7};
        *(f16x8*)(OUT + (size_t)node * 96 + l * 8) = wv;
    }
}

// --- aggregation, F=32, natural 64B rows, software-pipelined -------------------
__global__ __launch_bounds__(256) void k_agg32(const __half* __restrict__ Hp,
                                               const float* __restrict__ dinv,
                                               const int* __restrict__ rowptr,
                                               const int* __restrict__ adj,
                                               const float* __restrict__ bias,
                                               float* __restrict__ OUT, int n) {
    const int l = threadIdx.x & 63;
    const int node = blockIdx.x * 4 + (threadIdx.x >> 6);
    if (node >= n) return;
    const int g = l >> 3;
    const int li = l & 7;
    const float dn = dinv[node];
    const int e0 = rowptr[node], e1 = rowptr[node + 1];
    const f16x4* __restrict__ H4 = (const f16x4*)Hp;  // 8 f16x4 per row

    float acc[4] = {0.f, 0.f, 0.f, 0.f};

    int vs = 0;
    if (e0 < e1) vs = adj[min(e0 + (l & 7), e1 - 1)];

    {
        f16x4 v = H4[(size_t)node * 8 + li];
        float ws = (g == 0) ? 1.f : 0.f;
        #pragma unroll
        for (int i = 0; i < 4; ++i) acc[i] = fmaf((float)v[i], ws, acc[i]);
    }

    for (int e = e0; e < e1; e += 8) {
        int vs_next = vs;
        if (e + 8 < e1) vs_next = adj[min(e + 8 + (l & 7), e1 - 1)];
        int src = __shfl(vs, g, 64);
        float w = (e + g < e1) ? 1.f : 0.f;
        f16x4 v = H4[(size_t)src * 8 + li];
        #pragma unroll
        for (int i = 0; i < 4; ++i) acc[i] = fmaf((float)v[i], w, acc[i]);
        vs = vs_next;
    }

    #pragma unroll
    for (int i = 0; i < 4; ++i) {
        acc[i] += __shfl_xor(acc[i], 8, 64);
        acc[i] += __shfl_xor(acc[i], 16, 64);
        acc[i] += __shfl_xor(acc[i], 32, 64);
    }

    if (l < 8) {  // lane li owns features 4li..4li+3
        float4 bv = ((const float4*)bias)[l];
        float4 o = make_float4(acc[0] * dn + bv.x, acc[1] * dn + bv.y,
                               acc[2] * dn + bv.z, acc[3] * dn + bv.w);
        ((float4*)(OUT + (size_t)node * 32))[l] = o;
    }
}

// --- fused per-graph max+mean pool + log_softmax (block per graph) -------------
__global__ __launch_bounds__(256) void k_poollsm(const float* __restrict__ A,
                                                 const int* __restrict__ gstart,
                                                 float* __restrict__ out) {
    int g = blockIdx.x;
    int s0 = gstart[g], s1 = gstart[g + 1];
    int c = threadIdx.x & 31, k = threadIdx.x >> 5;
    float mx = -INFINITY, sm = 0.f;
    for (int nidx = s0 + k; nidx < s1; nidx += 8) {
        float v = A[(size_t)nidx * 32 + c];
        mx = fmaxf(mx, v);
        sm += v;
    }
    __shared__ float smx[8][32], ssm[8][32], pooled[64];
    smx[k][c] = mx;
    ssm[k][c] = sm;
    __syncthreads();
    if (threadIdx.x < 32) {
        float M = smx[0][c], S = ssm[0][c];
        #pragma unroll
        for (int kk = 1; kk < 8; ++kk) {
            M = fmaxf(M, smx[kk][c]);
            S += ssm[kk][c];
        }
        int cnt = s1 - s0;
        pooled[c] = M;
        pooled[32 + c] = S / fmaxf((float)cnt, 1.0f);
    }
    __syncthreads();
    if (threadIdx.x < 64) {   // first wave: 64-wide log_softmax
        int l = threadIdx.x;
        float v = pooled[l];
        float m = v;
        #pragma unroll
        for (int o = 32; o > 0; o >>= 1) m = fmaxf(m, __shfl_xor(m, o, 64));
        float e = __expf(v - m);
        float s = e;
        #pragma unroll
        for (int o = 32; o > 0; o >>= 1) s += __shfl_xor(s, o, 64);
        out[g * 64 + l] = v - m - __logf(s);
    }
}

// ---------------------------------------------------------------------------
extern "C" void kernel_launch(void* const* d_in, const int* in_sizes, int n_in,
                              void* d_out, int out_size, void* d_ws, size_t ws_size,
                              hipStream_t stream) {
    const float* x  = (const float*)d_in[0];
    const float* W0 = (const float*)d_in[1];
    const float* b0 = (const float*)d_in[2];
    const float* W1 = (const float*)d_in[3];
    const float* b1 = (const float*)d_in[4];
    const float* W2 = (const float*)d_in[5];
    const float* b2 = (const float*)d_in[6];
    const int* ei_raw    = (const int*)d_in[7];
    const int* batch_raw = (const int*)d_in[8];

    const int N = in_sizes[0] / 96;
    const int E = in_sizes[7] / 2;
    const int G = out_size / 64;
    const int NBUK = (N + 255) >> 8;          // 256 nodes/bucket, <=512 buckets
    float* out = (float*)d_out;

    char* ws = (char*)d_ws;
    size_t off = 0;
    auto alloc = [&](size_t bytes) -> void* {
        void* p = ws + off;
        off += (bytes + 255) & ~(size_t)255;
        return p;
    };
    __half*   Hp96    = (__half*)alloc((size_t)N * 96 * 2);   // gather table, 192B rows
    __half*   As16    = (__half*)alloc((size_t)N * 96 * 2);   // agg out, fp16 natural
    __half*   Hp32    = (__half*)alloc((size_t)N * 32 * 2);   // layer-2 table, 64B rows
    float*    D32     = (float*)alloc((size_t)N * 32 * 4);    // layer-2 agg out
    float*    dinv    = (float*)alloc((size_t)N * 4);
    int*      rowptr  = (int*)alloc((size_t)(N + 1) * 4);
    int*      adj     = (int*)alloc((size_t)E * 4);
    unsigned* ebuk    = (unsigned*)alloc((size_t)E * 4);      // bucket-sorted packed edges
    int*      bcnt    = (int*)alloc(512 * 4);
    int*      bstart  = (int*)alloc(513 * 4);
    int*      gcursor = (int*)alloc(512 * 4);
    int*      flag    = (int*)alloc(256);
    int*      gstart  = (int*)alloc((size_t)(G + 1) * 4);
    __half*   WT      = (__half*)alloc((size_t)21504 * 2);    // W0^T|W1^T|W2^T fp16

    (void)hipMemsetAsync(bcnt, 0, 512 * 4, stream);
    (void)hipMemsetAsync(gcursor, 0, 512 * 4, stream);

    // index dtype detection (conversion folded into consumers)
    k_detect<<<1, 256, 0, stream>>>(ei_raw, flag);

    // weight transpose+convert (one kernel for all 3)
    k_wt3<<<(21504 + 255) / 256, 256, 0, stream>>>(W0, W1, W2, WT);

    // CSR via bucket sort (reads raw edge indices directly)
    const int P2B = (E + 8191) / 8192;
    k_p1hist<<<P2B, 512, 0, stream>>>(ei_raw, flag, bcnt, E, NBUK);
    k_bscan<<<1, 512, 0, stream>>>(bcnt, bstart, NBUK, E);
    k_p2scatter<<<P2B, 512, 0, stream>>>(ei_raw, flag, bstart, gcursor, ebuk, E, NBUK);
    k_p3sort<<<NBUK, 256, 0, stream>>>(ebuk, bstart, adj, rowptr, dinv, N, E);
    k_gstart<<<1, 256, 0, stream>>>(batch_raw, flag, gstart, N, G);

    const int GB = (N + 63) / 64;
    const int AB = (N + 3) / 4;   // 4 nodes per agg block

    // layer 0: A = x fp32
    k_gemm_mfma<96, false><<<GB, 256, 0, stream>>>(x, (const __half*)nullptr, WT, dinv, Hp96, N);
    k_agg96<true><<<AB, 256, 0, stream>>>(Hp96, dinv, rowptr, adj, b0, As16, N);
    // layer 1: A = As16 fp16
    k_gemm_mfma<96, true><<<GB, 256, 0, stream>>>((const float*)nullptr, As16, WT + 9216, dinv, Hp96, N);
    k_agg96<true><<<AB, 256, 0, stream>>>(Hp96, dinv, rowptr, adj, b1, As16, N);
    // layer 2: A = As16 fp16
    k_gemm_mfma<32, true><<<GB, 256, 0, stream>>>((const float*)nullptr, As16, WT + 18432, dinv, Hp32, N);
    k_agg32<<<AB, 256, 0, stream>>>(Hp32, dinv, rowptr, adj, b2, D32, N);

    // fused pooling + log_softmax
    k_poollsm<<<G, 256, 0, stream>>>(D32, gstart, out);
}

// Round 14
// 248.301 us; speedup vs baseline: 1.1859x; 1.0132x over previous
//
#include <hip/hip_runtime.h>
#include <hip/hip_fp16.h>
#include <math.h>

// ---------------------------------------------------------------------------
// GCN: 3x (MFMA-fp16 GEMM -> sym-normalized neighbor aggregate) with SiLU,
// then per-graph max+mean pool and log_softmax.
// Round 14: round-13 structure + packed-fp16 accumulation in the agg inner
// loops (v_pk_fma_f16 via __hfma2): halves the FMA instruction count of the
// VALU-issue-bound gather kernels. Per-quarter chains are short (deg/4 + 1
// values) so fp16 accumulation costs ~3 ulp; cross-quarter reduction and
// epilogue remain fp32.
// ---------------------------------------------------------------------------

typedef _Float16 f16x8 __attribute__((ext_vector_type(8)));
typedef _Float16 f16x4 __attribute__((ext_vector_type(4)));
typedef float f32x4 __attribute__((ext_vector_type(4)));

static __device__ __forceinline__ float silu_f(float v) {
    return v / (1.0f + __expf(-v));
}

// raw index read honoring int64 (flagged) or int32 layout
static __device__ __forceinline__ int raw_at(const int* __restrict__ raw,
                                             int idx, int f64) {
    return raw[f64 ? 2 * idx : idx];
}

// --- int64-vs-int32 input detection -----------------------------------------
__global__ __launch_bounds__(256) void k_detect(const int* __restrict__ raw,
                                                int* __restrict__ flag) {
    __shared__ int anynz;
    if (threadIdx.x == 0) anynz = 0;
    __syncthreads();
    if (raw[2 * threadIdx.x + 1] != 0) anynz = 1;  // benign race, same value
    __syncthreads();
    if (threadIdx.x == 0) *flag = (anynz ? 0 : 1); // 1 => int64
}

// --- CSR pass 1: bucket histogram (bucket = dst>>8, <=512 buckets) -----------
__global__ __launch_bounds__(512) void k_p1hist(const int* __restrict__ eraw,
                                                const int* __restrict__ flag,
                                                int* __restrict__ bcnt,
                                                int E, int nbuk) {
    __shared__ int hs[512];
    const int t = threadIdx.x;
    const int f64 = flag[0];
    hs[t] = 0;
    __syncthreads();
    const int base = blockIdx.x * 8192;
    const int lim = min(base + 8192, E);
    for (int j = base + t; j < lim; j += 512)
        atomicAdd(&hs[raw_at(eraw, E + j, f64) >> 8], 1);
    __syncthreads();
    if (t < nbuk && hs[t]) atomicAdd(&bcnt[t], hs[t]);
}

// --- CSR pass 1b: exclusive scan of bucket counts -> bstart ------------------
__global__ __launch_bounds__(512) void k_bscan(const int* __restrict__ bcnt,
                                               int* __restrict__ bstart,
                                               int nbuk, int E) {
    __shared__ int lds[512];
    int t = threadIdx.x;
    int v = (t < nbuk) ? bcnt[t] : 0;
    lds[t] = v;
    __syncthreads();
    for (int off = 1; off < 512; off <<= 1) {
        int y = (t >= off) ? lds[t - off] : 0;
        __syncthreads();
        lds[t] += y;
        __syncthreads();
    }
    if (t < nbuk) bstart[t] = lds[t] - v;
    if (t == 0) bstart[nbuk] = E;
}

// --- CSR pass 2: bucket scatter, block-staged ---------------------------------
__global__ __launch_bounds__(512) void k_p2scatter(const int* __restrict__ eraw,
                                                   const int* __restrict__ flag,
                                                   const int* __restrict__ bstart,
                                                   int* __restrict__ gcursor,
                                                   unsigned* __restrict__ ebuk,
                                                   int E, int nbuk) {
    __shared__ int hs[512], sc[512], lexcl[512], pl[512], gb[512];
    __shared__ unsigned stg[8192];
    __shared__ unsigned short stb[8192];
    const int t = threadIdx.x;
    const int f64 = flag[0];
    const int base = blockIdx.x * 8192;
    const int len = min(8192, E - base);

    hs[t] = 0;
    __syncthreads();
    for (int j = t; j < len; j += 512)
        atomicAdd(&hs[raw_at(eraw, E + base + j, f64) >> 8], 1);
    __syncthreads();

    int cv = (t < nbuk) ? hs[t] : 0;
    sc[t] = cv;
    __syncthreads();
    for (int off = 1; off < 512; off <<= 1) {
        int y = (t >= off) ? sc[t - off] : 0;
        __syncthreads();
        sc[t] += y;
        __syncthreads();
    }
    int ex = sc[t] - cv;
    if (t < nbuk) {
        lexcl[t] = ex;
        pl[t] = ex;
        gb[t] = cv ? atomicAdd(&gcursor[t], cv) : 0;
    }
    __syncthreads();

    for (int j = t; j < len; j += 512) {
        int d = raw_at(eraw, E + base + j, f64);
        int s = raw_at(eraw, base + j, f64);
        int b = d >> 8;
        int slot = atomicAdd(&pl[b], 1);
        stg[slot] = ((unsigned)s << 8) | (unsigned)(d & 255);
        stb[slot] = (unsigned short)b;
    }
    __syncthreads();

    for (int s2 = t; s2 < len; s2 += 512) {
        int b = stb[s2];
        int gpos = bstart[b] + gb[b] + (s2 - lexcl[b]);
        ebuk[gpos] = stg[s2];
    }
}

// --- CSR pass 3: per-bucket counting sort -> adj, rowptr, dinv ----------------
__global__ __launch_bounds__(256) void k_p3sort(const unsigned* __restrict__ ebuk,
                                                const int* __restrict__ bstart,
                                                int* __restrict__ adj,
                                                int* __restrict__ rowptr,
                                                float* __restrict__ dinv,
                                                int n, int E) {
    const int b = blockIdx.x;
    const int t = threadIdx.x;
    const int s0 = bstart[b], s1 = bstart[b + 1];
    __shared__ int cs[256], pl[256];
    cs[t] = 0;
    __syncthreads();
    for (int j = s0 + t; j < s1; j += 256)
        atomicAdd(&cs[ebuk[j] & 255], 1);
    __syncthreads();
    int cv = cs[t];
    pl[t] = cv;
    __syncthreads();
    for (int off = 1; off < 256; off <<= 1) {
        int y = (t >= off) ? pl[t - off] : 0;
        __syncthreads();
        pl[t] += y;
        __syncthreads();
    }
    int ex = pl[t] - cv;
    __syncthreads();
    pl[t] = ex;
    int node = (b << 8) + t;
    if (node < n) {
        rowptr[node] = s0 + ex;
        dinv[node] = rsqrtf((float)cv + 1.0f);  // +1 self loop
    }
    if (b == 0 && t == 0) rowptr[n] = E;
    __syncthreads();
    for (int j = s0 + t; j < s1; j += 256) {
        unsigned p = ebuk[j];
        int slot = atomicAdd(&pl[p & 255], 1);
        adj[s0 + slot] = (int)(p >> 8);
    }
}

// --- per-graph boundaries (batch is sorted; raw int64/int32) -------------------
__global__ __launch_bounds__(256) void k_gstart(const int* __restrict__ braw,
                                                const int* __restrict__ flag,
                                                int* __restrict__ gstart,
                                                int n, int G) {
    int t = threadIdx.x;
    if (t > G) return;
    const int f64 = flag[0];
    int lo = 0, hi = n;
    while (lo < hi) {
        int mid = (lo + hi) >> 1;
        if (raw_at(braw, mid, f64) < t) lo = mid + 1; else hi = mid;
    }
    gstart[t] = lo;
}

// --- fused W transpose + fp16 convert for all 3 weights ------------------------
// WT arena: [0,9216) = W0^T (96x96), [9216,18432) = W1^T, [18432,21504) = W2^T.
__global__ __launch_bounds__(256) void k_wt3(const float* __restrict__ W0,
                                             const float* __restrict__ W1,
                                             const float* __restrict__ W2,
                                             __half* __restrict__ WT) {
    int idx = blockIdx.x * 256 + threadIdx.x;
    if (idx >= 21504) return;
    const float* W;
    int fout, loc;
    if (idx < 9216)       { W = W0; fout = 96; loc = idx; }
    else if (idx < 18432) { W = W1; fout = 96; loc = idx - 9216; }
    else                  { W = W2; fout = 32; loc = idx - 18432; }
    int nn = loc / 96, kk = loc - nn * 96;
    WT[idx] = __float2half(W[kk * fout + nn]);
}

// --- MFMA GEMM: H[r,:] = fp16( dinv[r] * (A[r,:96] @ W) ), LDS-free ----------
template <int FOUT, bool AHALF>
__global__ __launch_bounds__(256) void k_gemm_mfma(const float* __restrict__ Xf,
                                                   const __half* __restrict__ Xh,
                                                   const __half* __restrict__ WT,
                                                   const float* __restrict__ dinv,
                                                   __half* __restrict__ H, int n) {
    const int l = threadIdx.x & 63;
    const int w = threadIdx.x >> 6;
    const int row0 = blockIdx.x * 64 + w * 16;
    const int lr = l & 15, lg = l >> 4;
    constexpr int NT = FOUT / 16;

    f16x8 bfrag[NT][3];
    #pragma unroll
    for (int t = 0; t < NT; ++t)
        #pragma unroll
        for (int kk = 0; kk < 3; ++kk)
            bfrag[t][kk] = *(const f16x8*)&WT[(t * 16 + lr) * 96 + kk * 32 + lg * 8];

    f32x4 acc[NT];
    #pragma unroll
    for (int t = 0; t < NT; ++t) acc[t] = (f32x4){0.f, 0.f, 0.f, 0.f};

    int arow = row0 + lr;
    int arow_c = arow < n ? arow : n - 1;  // clamp; garbage rows never stored

    #pragma unroll
    for (int kk = 0; kk < 3; ++kk) {
        f16x8 af;
        if (AHALF) {
            af = *(const f16x8*)(Xh + (size_t)arow_c * 96 + kk * 32 + lg * 8);
        } else {
            const float* xr = Xf + (size_t)arow_c * 96;
            float4 u0 = *(const float4*)&xr[kk * 32 + lg * 8];
            float4 u1 = *(const float4*)&xr[kk * 32 + lg * 8 + 4];
            af[0] = (_Float16)u0.x; af[1] = (_Float16)u0.y;
            af[2] = (_Float16)u0.z; af[3] = (_Float16)u0.w;
            af[4] = (_Float16)u1.x; af[5] = (_Float16)u1.y;
            af[6] = (_Float16)u1.z; af[7] = (_Float16)u1.w;
        }
        #pragma unroll
        for (int t = 0; t < NT; ++t)
            acc[t] = __builtin_amdgcn_mfma_f32_16x16x32_f16(af, bfrag[t][kk], acc[t], 0, 0, 0);
    }

    // C/D: col = t*16+lr, row = row0 + lg*4 + i  (m89-verified map)
    #pragma unroll
    for (int i = 0; i < 4; ++i) {
        int r = row0 + lg * 4 + i;
        if (r < n) {
            float dv = dinv[r];
            #pragma unroll
            for (int t = 0; t < NT; ++t)
                H[(size_t)r * FOUT + t * 16 + lr] = __float2half(acc[t][i] * dv);
        }
    }
}

// --- aggregation, F=96, UNPADDED 192B rows, packed-fp16 accumulation ----------
// One wave per node. Quarter q = l>>4 owns 2 edge-chains; lane li = l&15:
// li<12 loads octet li (f16x8); li>=12 clamps to octet li-12. 8 edges/iter;
// next adj vector prefetched during FMAs. Inner accumulate = 8 x v_pk_fma_f16
// per iter (halved vs fp32 mix-FMA); per-quarter chains are ~deg/4+1 long so
// fp16 accumulation error is ~3 ulp. Cross-quarter reduce + epilogue in fp32.
template <bool SILU>
__global__ __launch_bounds__(256) void k_agg96(const __half* __restrict__ Hp,
                                               const float* __restrict__ dinv,
                                               const int* __restrict__ rowptr,
                                               const int* __restrict__ adj,
                                               const float* __restrict__ bias,
                                               __half* __restrict__ OUT, int n) {
    const int l = threadIdx.x & 63;
    const int node = blockIdx.x * 4 + (threadIdx.x >> 6);
    if (node >= n) return;
    const int q = l >> 4;
    const int li = l & 15;
    const int oct = li < 12 ? li : li - 12;   // octet within row (broadcast for pads)
    const float dn = dinv[node];
    const int e0 = rowptr[node], e1 = rowptr[node + 1];
    const f16x8* __restrict__ H8 = (const f16x8*)Hp;  // 12 f16x8 per row

    const __half2 one2 = __float2half2_rn(1.f);
    const __half2 zero2 = __float2half2_rn(0.f);

    __half2 hacc[4];
    #pragma unroll
    for (int i = 0; i < 4; ++i) hacc[i] = zero2;

    // prologue: first adj vector (uniform guard; deg=0 safe)
    int vs = 0;
    if (e0 < e1) vs = adj[min(e0 + (l & 7), e1 - 1)];

    // self row (counted once, quarter 0) — load overlaps first adj fetch
    {
        f16x8 v = H8[(size_t)node * 12 + oct];
        const __half2* vh = (const __half2*)&v;
        __half2 ws = (q == 0) ? one2 : zero2;
        #pragma unroll
        for (int i = 0; i < 4; ++i) hacc[i] = __hfma2(vh[i], ws, hacc[i]);
    }

    for (int e = e0; e < e1; e += 8) {
        int vs_next = vs;
        if (e + 8 < e1) vs_next = adj[min(e + 8 + (l & 7), e1 - 1)];  // prefetch
        int s0 = __shfl(vs, q, 64);
        int s1 = __shfl(vs, 4 + q, 64);
        __half2 w0 = (e + q < e1) ? one2 : zero2;
        __half2 w1 = (e + 4 + q < e1) ? one2 : zero2;
        f16x8 v0 = H8[(size_t)s0 * 12 + oct];   // both gathers in flight
        f16x8 v1 = H8[(size_t)s1 * 12 + oct];
        const __half2* vh0 = (const __half2*)&v0;
        const __half2* vh1 = (const __half2*)&v1;
        #pragma unroll
        for (int i = 0; i < 4; ++i) hacc[i] = __hfma2(vh0[i], w0, hacc[i]);
        #pragma unroll
        for (int i = 0; i < 4; ++i) hacc[i] = __hfma2(vh1[i], w1, hacc[i]);
        vs = vs_next;
    }

    // convert to fp32, then reduce across quarters (same-li lanes)
    float acc[8];
    #pragma unroll
    for (int i = 0; i < 4; ++i) {
        float2 f = __half22float2(hacc[i]);
        acc[2 * i] = f.x;
        acc[2 * i + 1] = f.y;
    }
    #pragma unroll
    for (int i = 0; i < 8; ++i) {
        acc[i] += __shfl_xor(acc[i], 16, 64);
        acc[i] += __shfl_xor(acc[i], 32, 64);
    }

    if (l < 12) {  // q==0, li<12: lane li owns features 8li..8li+7
        float4 bv0 = ((const float4*)bias)[2 * l];
        float4 bv1 = ((const float4*)bias)[2 * l + 1];
        float o0 = acc[0] * dn + bv0.x, o1 = acc[1] * dn + bv0.y;
        float o2 = acc[2] * dn + bv0.z, o3 = acc[3] * dn + bv0.w;
        float o4 = acc[4] * dn + bv1.x, o5 = acc[5] * dn + bv1.y;
        float o6 = acc[6] * dn + bv1.z, o7 = acc[7] * dn + bv1.w;
        if (SILU) {
            o0 = silu_f(o0); o1 = silu_f(o1); o2 = silu_f(o2); o3 = silu_f(o3);
            o4 = silu_f(o4); o5 = silu_f(o5); o6 = silu_f(o6); o7 = silu_f(o7);
        }
        f16x8 wv = {(_Float16)o0, (_Float16)o1, (_Float16)o2, (_Float16)o3,
                    (_Float16)o4, (_Float16)o5, (_Float16)o6, (_Float16)o7};
        *(f16x8*)(OUT + (size_t)node * 96 + l * 8) = wv;
    }
}

// --- aggregation, F=32, natural 64B rows, packed-fp16 accumulation -------------
__global__ __launch_bounds__(256) void k_agg32(const __half* __restrict__ Hp,
                                               const float* __restrict__ dinv,
                                               const int* __restrict__ rowptr,
                                               const int* __restrict__ adj,
                                               const float* __restrict__ bias,
                                               float* __restrict__ OUT, int n) {
    const int l = threadIdx.x & 63;
    const int node = blockIdx.x * 4 + (threadIdx.x >> 6);
    if (node >= n) return;
    const int g = l >> 3;
    const int li = l & 7;
    const float dn = dinv[node];
    const int e0 = rowptr[node], e1 = rowptr[node + 1];
    const f16x4* __restrict__ H4 = (const f16x4*)Hp;  // 8 f16x4 per row

    const __half2 one2 = __float2half2_rn(1.f);
    const __half2 zero2 = __float2half2_rn(0.f);

    __half2 hacc[2] = {zero2, zero2};

    int vs = 0;
    if (e0 < e1) vs = adj[min(e0 + (l & 7), e1 - 1)];

    {
        f16x4 v = H4[(size_t)node * 8 + li];
        const __half2* vh = (const __half2*)&v;
        __half2 ws = (g == 0) ? one2 : zero2;
        #pragma unroll
        for (int i = 0; i < 2; ++i) hacc[i] = __hfma2(vh[i], ws, hacc[i]);
    }

    for (int e = e0; e < e1; e += 8) {
        int vs_next = vs;
        if (e + 8 < e1) vs_next = adj[min(e + 8 + (l & 7), e1 - 1)];
        int src = __shfl(vs, g, 64);
        __half2 w = (e + g < e1) ? one2 : zero2;
        f16x4 v = H4[(size_t)src * 8 + li];
        const __half2* vh = (const __half2*)&v;
        #pragma unroll
        for (int i = 0; i < 2; ++i) hacc[i] = __hfma2(vh[i], w, hacc[i]);
        vs = vs_next;
    }

    float acc[4];
    #pragma unroll
    for (int i = 0; i < 2; ++i) {
        float2 f = __half22float2(hacc[i]);
        acc[2 * i] = f.x;
        acc[2 * i + 1] = f.y;
    }
    #pragma unroll
    for (int i = 0; i < 4; ++i) {
        acc[i] += __shfl_xor(acc[i], 8, 64);
        acc[i] += __shfl_xor(acc[i], 16, 64);
        acc[i] += __shfl_xor(acc[i], 32, 64);
    }

    if (l < 8) {  // lane li owns features 4li..4li+3
        float4 bv = ((const float4*)bias)[l];
        float4 o = make_float4(acc[0] * dn + bv.x, acc[1] * dn + bv.y,
                               acc[2] * dn + bv.z, acc[3] * dn + bv.w);
        ((float4*)(OUT + (size_t)node * 32))[l] = o;
    }
}

// --- fused per-graph max+mean pool + log_softmax (block per graph) -------------
__global__ __launch_bounds__(256) void k_poollsm(const float* __restrict__ A,
                                                 const int* __restrict__ gstart,
                                                 float* __restrict__ out) {
    int g = blockIdx.x;
    int s0 = gstart[g], s1 = gstart[g + 1];
    int c = threadIdx.x & 31, k = threadIdx.x >> 5;
    float mx = -INFINITY, sm = 0.f;
    for (int nidx = s0 + k; nidx < s1; nidx += 8) {
        float v = A[(size_t)nidx * 32 + c];
        mx = fmaxf(mx, v);
        sm += v;
    }
    __shared__ float smx[8][32], ssm[8][32], pooled[64];
    smx[k][c] = mx;
    ssm[k][c] = sm;
    __syncthreads();
    if (threadIdx.x < 32) {
        float M = smx[0][c], S = ssm[0][c];
        #pragma unroll
        for (int kk = 1; kk < 8; ++kk) {
            M = fmaxf(M, smx[kk][c]);
            S += ssm[kk][c];
        }
        int cnt = s1 - s0;
        pooled[c] = M;
        pooled[32 + c] = S / fmaxf((float)cnt, 1.0f);
    }
    __syncthreads();
    if (threadIdx.x < 64) {   // first wave: 64-wide log_softmax
        int l = threadIdx.x;
        float v = pooled[l];
        float m = v;
        #pragma unroll
        for (int o = 32; o > 0; o >>= 1) m = fmaxf(m, __shfl_xor(m, o, 64));
        float e = __expf(v - m);
        float s = e;
        #pragma unroll
        for (int o = 32; o > 0; o >>= 1) s += __shfl_xor(s, o, 64);
        out[g * 64 + l] = v - m - __logf(s);
    }
}

// ---------------------------------------------------------------------------
extern "C" void kernel_launch(void* const* d_in, const int* in_sizes, int n_in,
                              void* d_out, int out_size, void* d_ws, size_t ws_size,
                              hipStream_t stream) {
    const float* x  = (const float*)d_in[0];
    const float* W0 = (const float*)d_in[1];
    const float* b0 = (const float*)d_in[2];
    const float* W1 = (const float*)d_in[3];
    const float* b1 = (const float*)d_in[4];
    const float* W2 = (const float*)d_in[5];
    const float* b2 = (const float*)d_in[6];
    const int* ei_raw    = (const int*)d_in[7];
    const int* batch_raw = (const int*)d_in[8];

    const int N = in_sizes[0] / 96;
    const int E = in_sizes[7] / 2;
    const int G = out_size / 64;
    const int NBUK = (N + 255) >> 8;          // 256 nodes/bucket, <=512 buckets
    float* out = (float*)d_out;

    char* ws = (char*)d_ws;
    size_t off = 0;
    auto alloc = [&](size_t bytes) -> void* {
        void* p = ws + off;
        off += (bytes + 255) & ~(size_t)255;
        return p;
    };
    __half*   Hp96    = (__half*)alloc((size_t)N * 96 * 2);   // gather table, 192B rows
    __half*   As16    = (__half*)alloc((size_t)N * 96 * 2);   // agg out, fp16 natural
    __half*   Hp32    = (__half*)alloc((size_t)N * 32 * 2);   // layer-2 table, 64B rows
    float*    D32     = (float*)alloc((size_t)N * 32 * 4);    // layer-2 agg out
    float*    dinv    = (float*)alloc((size_t)N * 4);
    int*      rowptr  = (int*)alloc((size_t)(N + 1) * 4);
    int*      adj     = (int*)alloc((size_t)E * 4);
    unsigned* ebuk    = (unsigned*)alloc((size_t)E * 4);      // bucket-sorted packed edges
    int*      bcnt    = (int*)alloc(512 * 4);
    int*      bstart  = (int*)alloc(513 * 4);
    int*      gcursor = (int*)alloc(512 * 4);
    int*      flag    = (int*)alloc(256);
    int*      gstart  = (int*)alloc((size_t)(G + 1) * 4);
    __half*   WT      = (__half*)alloc((size_t)21504 * 2);    // W0^T|W1^T|W2^T fp16

    (void)hipMemsetAsync(bcnt, 0, 512 * 4, stream);
    (void)hipMemsetAsync(gcursor, 0, 512 * 4, stream);

    // index dtype detection (conversion folded into consumers)
    k_detect<<<1, 256, 0, stream>>>(ei_raw, flag);

    // weight transpose+convert (one kernel for all 3)
    k_wt3<<<(21504 + 255) / 256, 256, 0, stream>>>(W0, W1, W2, WT);

    // CSR via bucket sort (reads raw edge indices directly)
    const int P2B = (E + 8191) / 8192;
    k_p1hist<<<P2B, 512, 0, stream>>>(ei_raw, flag, bcnt, E, NBUK);
    k_bscan<<<1, 512, 0, stream>>>(bcnt, bstart, NBUK, E);
    k_p2scatter<<<P2B, 512, 0, stream>>>(ei_raw, flag, bstart, gcursor, ebuk, E, NBUK);
    k_p3sort<<<NBUK, 256, 0, stream>>>(ebuk, bstart, adj, rowptr, dinv, N, E);
    k_gstart<<<1, 256, 0, stream>>>(batch_raw, flag, gstart, N, G);

    const int GB = (N + 63) / 64;
    const int AB = (N + 3) / 4;   // 4 nodes per agg block

    // layer 0: A = x fp32
    k_gemm_mfma<96, false><<<GB, 256, 0, stream>>>(x, (const __half*)nullptr, WT, dinv, Hp96, N);
    k_agg96<true><<<AB, 256, 0, stream>>>(Hp96, dinv, rowptr, adj, b0, As16, N);
    // layer 1: A = As16 fp16
    k_gemm_mfma<96, true><<<GB, 256, 0, stream>>>((const float*)nullptr, As16, WT + 9216, dinv, Hp96, N);
    k_agg96<true><<<AB, 256, 0, stream>>>(Hp96, dinv, rowptr, adj, b1, As16, N);
    // layer 2: A = As16 fp16
    k_gemm_mfma<32, true><<<GB, 256, 0, stream>>>((const float*)nullptr, As16, WT + 18432, dinv, Hp32, N);
    k_agg32<<<AB, 256, 0, stream>>>(Hp32, dinv, rowptr, adj, b2, D32, N);

    // fused pooling + log_softmax
    k_poollsm<<<G, 256, 0, stream>>>(D32, gstart, out);
}

// Round 15
// 205.727 us; speedup vs baseline: 1.4314x; 1.2069x over previous
//
#include <hip/hip_runtime.h>
#include <hip/hip_fp16.h>
#include <math.h>

// ---------------------------------------------------------------------------
// GCN: 3x (MFMA-fp16 GEMM -> sym-normalized neighbor aggregate) with SiLU,
// then per-graph max+mean pool and log_softmax.
// Round 15: agg restructured to ONE NODE PER 16-LANE QUARTER (4 nodes/wave;
// agg32: 8 nodes/wave). Eliminates the 24-instr cross-quarter reduce and
// amortizes epilogue/prologue 4x (VALU instrs/node ~88 -> ~37; the agg was
// VALU-issue-bound at ~70% busy). Each quarter walks its own edge list
// serially from a staged 16-edge adj vector, 2x-unrolled gathers.
// Memory behavior unchanged: one gather instruction = 4 distinct rows.
// ---------------------------------------------------------------------------

typedef _Float16 f16x8 __attribute__((ext_vector_type(8)));
typedef _Float16 f16x4 __attribute__((ext_vector_type(4)));
typedef float f32x4 __attribute__((ext_vector_type(4)));

static __device__ __forceinline__ float silu_f(float v) {
    return v / (1.0f + __expf(-v));
}

// raw index read honoring int64 (flagged) or int32 layout
static __device__ __forceinline__ int raw_at(const int* __restrict__ raw,
                                             int idx, int f64) {
    return raw[f64 ? 2 * idx : idx];
}

// --- int64-vs-int32 input detection -----------------------------------------
__global__ __launch_bounds__(256) void k_detect(const int* __restrict__ raw,
                                                int* __restrict__ flag) {
    __shared__ int anynz;
    if (threadIdx.x == 0) anynz = 0;
    __syncthreads();
    if (raw[2 * threadIdx.x + 1] != 0) anynz = 1;  // benign race, same value
    __syncthreads();
    if (threadIdx.x == 0) *flag = (anynz ? 0 : 1); // 1 => int64
}

// --- CSR pass 1: bucket histogram (bucket = dst>>8, <=512 buckets) -----------
__global__ __launch_bounds__(512) void k_p1hist(const int* __restrict__ eraw,
                                                const int* __restrict__ flag,
                                                int* __restrict__ bcnt,
                                                int E, int nbuk) {
    __shared__ int hs[512];
    const int t = threadIdx.x;
    const int f64 = flag[0];
    hs[t] = 0;
    __syncthreads();
    const int base = blockIdx.x * 8192;
    const int lim = min(base + 8192, E);
    for (int j = base + t; j < lim; j += 512)
        atomicAdd(&hs[raw_at(eraw, E + j, f64) >> 8], 1);
    __syncthreads();
    if (t < nbuk && hs[t]) atomicAdd(&bcnt[t], hs[t]);
}

// --- CSR pass 1b: exclusive scan of bucket counts -> bstart ------------------
__global__ __launch_bounds__(512) void k_bscan(const int* __restrict__ bcnt,
                                               int* __restrict__ bstart,
                                               int nbuk, int E) {
    __shared__ int lds[512];
    int t = threadIdx.x;
    int v = (t < nbuk) ? bcnt[t] : 0;
    lds[t] = v;
    __syncthreads();
    for (int off = 1; off < 512; off <<= 1) {
        int y = (t >= off) ? lds[t - off] : 0;
        __syncthreads();
        lds[t] += y;
        __syncthreads();
    }
    if (t < nbuk) bstart[t] = lds[t] - v;
    if (t == 0) bstart[nbuk] = E;
}

// --- CSR pass 2: bucket scatter, block-staged ---------------------------------
__global__ __launch_bounds__(512) void k_p2scatter(const int* __restrict__ eraw,
                                                   const int* __restrict__ flag,
                                                   const int* __restrict__ bstart,
                                                   int* __restrict__ gcursor,
                                                   unsigned* __restrict__ ebuk,
                                                   int E, int nbuk) {
    __shared__ int hs[512], sc[512], lexcl[512], pl[512], gb[512];
    __shared__ unsigned stg[8192];
    __shared__ unsigned short stb[8192];
    const int t = threadIdx.x;
    const int f64 = flag[0];
    const int base = blockIdx.x * 8192;
    const int len = min(8192, E - base);

    hs[t] = 0;
    __syncthreads();
    for (int j = t; j < len; j += 512)
        atomicAdd(&hs[raw_at(eraw, E + base + j, f64) >> 8], 1);
    __syncthreads();

    int cv = (t < nbuk) ? hs[t] : 0;
    sc[t] = cv;
    __syncthreads();
    for (int off = 1; off < 512; off <<= 1) {
        int y = (t >= off) ? sc[t - off] : 0;
        __syncthreads();
        sc[t] += y;
        __syncthreads();
    }
    int ex = sc[t] - cv;
    if (t < nbuk) {
        lexcl[t] = ex;
        pl[t] = ex;
        gb[t] = cv ? atomicAdd(&gcursor[t], cv) : 0;
    }
    __syncthreads();

    for (int j = t; j < len; j += 512) {
        int d = raw_at(eraw, E + base + j, f64);
        int s = raw_at(eraw, base + j, f64);
        int b = d >> 8;
        int slot = atomicAdd(&pl[b], 1);
        stg[slot] = ((unsigned)s << 8) | (unsigned)(d & 255);
        stb[slot] = (unsigned short)b;
    }
    __syncthreads();

    for (int s2 = t; s2 < len; s2 += 512) {
        int b = stb[s2];
        int gpos = bstart[b] + gb[b] + (s2 - lexcl[b]);
        ebuk[gpos] = stg[s2];
    }
}

// --- CSR pass 3: per-bucket counting sort -> adj, rowptr, dinv ----------------
__global__ __launch_bounds__(256) void k_p3sort(const unsigned* __restrict__ ebuk,
                                                const int* __restrict__ bstart,
                                                int* __restrict__ adj,
                                                int* __restrict__ rowptr,
                                                float* __restrict__ dinv,
                                                int n, int E) {
    const int b = blockIdx.x;
    const int t = threadIdx.x;
    const int s0 = bstart[b], s1 = bstart[b + 1];
    __shared__ int cs[256], pl[256];
    cs[t] = 0;
    __syncthreads();
    for (int j = s0 + t; j < s1; j += 256)
        atomicAdd(&cs[ebuk[j] & 255], 1);
    __syncthreads();
    int cv = cs[t];
    pl[t] = cv;
    __syncthreads();
    for (int off = 1; off < 256; off <<= 1) {
        int y = (t >= off) ? pl[t - off] : 0;
        __syncthreads();
        pl[t] += y;
        __syncthreads();
    }
    int ex = pl[t] - cv;
    __syncthreads();
    pl[t] = ex;
    int node = (b << 8) + t;
    if (node < n) {
        rowptr[node] = s0 + ex;
        dinv[node] = rsqrtf((float)cv + 1.0f);  // +1 self loop
    }
    if (b == 0 && t == 0) rowptr[n] = E;
    __syncthreads();
    for (int j = s0 + t; j < s1; j += 256) {
        unsigned p = ebuk[j];
        int slot = atomicAdd(&pl[p & 255], 1);
        adj[s0 + slot] = (int)(p >> 8);
    }
}

// --- per-graph boundaries (batch is sorted; raw int64/int32) -------------------
__global__ __launch_bounds__(256) void k_gstart(const int* __restrict__ braw,
                                                const int* __restrict__ flag,
                                                int* __restrict__ gstart,
                                                int n, int G) {
    int t = threadIdx.x;
    if (t > G) return;
    const int f64 = flag[0];
    int lo = 0, hi = n;
    while (lo < hi) {
        int mid = (lo + hi) >> 1;
        if (raw_at(braw, mid, f64) < t) lo = mid + 1; else hi = mid;
    }
    gstart[t] = lo;
}

// --- fused W transpose + fp16 convert for all 3 weights ------------------------
// WT arena: [0,9216) = W0^T (96x96), [9216,18432) = W1^T, [18432,21504) = W2^T.
__global__ __launch_bounds__(256) void k_wt3(const float* __restrict__ W0,
                                             const float* __restrict__ W1,
                                             const float* __restrict__ W2,
                                             __half* __restrict__ WT) {
    int idx = blockIdx.x * 256 + threadIdx.x;
    if (idx >= 21504) return;
    const float* W;
    int fout, loc;
    if (idx < 9216)       { W = W0; fout = 96; loc = idx; }
    else if (idx < 18432) { W = W1; fout = 96; loc = idx - 9216; }
    else                  { W = W2; fout = 32; loc = idx - 18432; }
    int nn = loc / 96, kk = loc - nn * 96;
    WT[idx] = __float2half(W[kk * fout + nn]);
}

// --- MFMA GEMM: H[r,:] = fp16( dinv[r] * (A[r,:96] @ W) ), LDS-free ----------
template <int FOUT, bool AHALF>
__global__ __launch_bounds__(256) void k_gemm_mfma(const float* __restrict__ Xf,
                                                   const __half* __restrict__ Xh,
                                                   const __half* __restrict__ WT,
                                                   const float* __restrict__ dinv,
                                                   __half* __restrict__ H, int n) {
    const int l = threadIdx.x & 63;
    const int w = threadIdx.x >> 6;
    const int row0 = blockIdx.x * 64 + w * 16;
    const int lr = l & 15, lg = l >> 4;
    constexpr int NT = FOUT / 16;

    f16x8 bfrag[NT][3];
    #pragma unroll
    for (int t = 0; t < NT; ++t)
        #pragma unroll
        for (int kk = 0; kk < 3; ++kk)
            bfrag[t][kk] = *(const f16x8*)&WT[(t * 16 + lr) * 96 + kk * 32 + lg * 8];

    f32x4 acc[NT];
    #pragma unroll
    for (int t = 0; t < NT; ++t) acc[t] = (f32x4){0.f, 0.f, 0.f, 0.f};

    int arow = row0 + lr;
    int arow_c = arow < n ? arow : n - 1;  // clamp; garbage rows never stored

    #pragma unroll
    for (int kk = 0; kk < 3; ++kk) {
        f16x8 af;
        if (AHALF) {
            af = *(const f16x8*)(Xh + (size_t)arow_c * 96 + kk * 32 + lg * 8);
        } else {
            const float* xr = Xf + (size_t)arow_c * 96;
            float4 u0 = *(const float4*)&xr[kk * 32 + lg * 8];
            float4 u1 = *(const float4*)&xr[kk * 32 + lg * 8 + 4];
            af[0] = (_Float16)u0.x; af[1] = (_Float16)u0.y;
            af[2] = (_Float16)u0.z; af[3] = (_Float16)u0.w;
            af[4] = (_Float16)u1.x; af[5] = (_Float16)u1.y;
            af[6] = (_Float16)u1.z; af[7] = (_Float16)u1.w;
        }
        #pragma unroll
        for (int t = 0; t < NT; ++t)
            acc[t] = __builtin_amdgcn_mfma_f32_16x16x32_f16(af, bfrag[t][kk], acc[t], 0, 0, 0);
    }

    // C/D: col = t*16+lr, row = row0 + lg*4 + i  (m89-verified map)
    #pragma unroll
    for (int i = 0; i < 4; ++i) {
        int r = row0 + lg * 4 + i;
        if (r < n) {
            float dv = dinv[r];
            #pragma unroll
            for (int t = 0; t < NT; ++t)
                H[(size_t)r * FOUT + t * 16 + lr] = __float2half(acc[t][i] * dv);
        }
    }
}

// --- aggregation, F=96: ONE NODE PER QUARTER (4 nodes/wave) --------------------
// Quarter q = l>>4 owns node base+q; lane li = l&15: li<12 loads octet li of
// the gathered row (f16x8); li>=12 clamps to octet li-12 (broadcast, unused).
// Quarter's next 16 edges staged in its lanes; per iteration 1 edge/node
// (4 edges wave-wide), 2x unrolled. No cross-lane reduce; epilogue runs for
// all 4 nodes in parallel. fp16 packed accumulation; fp32 epilogue.
template <bool SILU>
__global__ __launch_bounds__(256) void k_agg96(const __half* __restrict__ Hp,
                                               const float* __restrict__ dinv,
                                               const int* __restrict__ rowptr,
                                               const int* __restrict__ adj,
                                               const float* __restrict__ bias,
                                               __half* __restrict__ OUT, int n) {
    const int l = threadIdx.x & 63;
    const int li = l & 15;
    const int oct = li < 12 ? li : li - 12;
    const int node = blockIdx.x * 16 + (threadIdx.x >> 6) * 4 + (l >> 4);
    const int nodec = node < n ? node : n - 1;
    const float dn = dinv[nodec];
    const int e0 = rowptr[nodec];
    const int deg = rowptr[nodec + 1] - e0;
    const f16x8* __restrict__ H8 = (const f16x8*)Hp;  // 12 f16x8 per row

    // wave-max degree across the 4 quarters
    int dmax = deg;
    dmax = max(dmax, __shfl_xor(dmax, 16, 64));
    dmax = max(dmax, __shfl_xor(dmax, 32, 64));

    const __half2 one2 = __float2half2_rn(1.f);
    const __half2 zero2 = __float2half2_rn(0.f);

    // stage this quarter's next 16 edges (clamped; deg=0 -> row 0, masked)
    int vs = 0;
    if (deg > 0) vs = adj[min(e0 + li, e0 + deg - 1)];

    // init accumulator with self row (once per quarter = once per node)
    __half2 hacc[4];
    {
        f16x8 v = H8[(size_t)nodec * 12 + oct];
        const __half2* vh = (const __half2*)&v;
        #pragma unroll
        for (int i = 0; i < 4; ++i) hacc[i] = vh[i];
    }

    const int qbase = l & 48;
    for (int j = 0; j < dmax; j += 2) {
        int s0 = __shfl(vs, qbase | (j & 15), 64);
        int s1 = __shfl(vs, qbase | ((j + 1) & 15), 64);
        __half2 w0 = (j < deg) ? one2 : zero2;
        __half2 w1 = (j + 1 < deg) ? one2 : zero2;
        f16x8 v0 = H8[(size_t)s0 * 12 + oct];
        f16x8 v1 = H8[(size_t)s1 * 12 + oct];
        if ((j & 15) == 14 && j + 2 < dmax && deg > 0)
            vs = adj[min(e0 + j + 2 + li, e0 + deg - 1)];  // refill next 16
        const __half2* vh0 = (const __half2*)&v0;
        const __half2* vh1 = (const __half2*)&v1;
        #pragma unroll
        for (int i = 0; i < 4; ++i) hacc[i] = __hfma2(vh0[i], w0, hacc[i]);
        #pragma unroll
        for (int i = 0; i < 4; ++i) hacc[i] = __hfma2(vh1[i], w1, hacc[i]);
    }

    if (li < 12 && node < n) {  // lane li owns features 8li..8li+7 of its node
        float acc[8];
        #pragma unroll
        for (int i = 0; i < 4; ++i) {
            float2 f = __half22float2(hacc[i]);
            acc[2 * i] = f.x;
            acc[2 * i + 1] = f.y;
        }
        float4 bv0 = ((const float4*)bias)[2 * li];
        float4 bv1 = ((const float4*)bias)[2 * li + 1];
        float o0 = acc[0] * dn + bv0.x, o1 = acc[1] * dn + bv0.y;
        float o2 = acc[2] * dn + bv0.z, o3 = acc[3] * dn + bv0.w;
        float o4 = acc[4] * dn + bv1.x, o5 = acc[5] * dn + bv1.y;
        float o6 = acc[6] * dn + bv1.z, o7 = acc[7] * dn + bv1.w;
        if (SILU) {
            o0 = silu_f(o0); o1 = silu_f(o1); o2 = silu_f(o2); o3 = silu_f(o3);
            o4 = silu_f(o4); o5 = silu_f(o5); o6 = silu_f(o6); o7 = silu_f(o7);
        }
        f16x8 wv = {(_Float16)o0, (_Float16)o1, (_Float16)o2, (_Float16)o3,
                    (_Float16)o4, (_Float16)o5, (_Float16)o6, (_Float16)o7};
        *(f16x8*)(OUT + (size_t)node * 96 + li * 8) = wv;
    }
}

// --- aggregation, F=32: ONE NODE PER 8-LANE GROUP (8 nodes/wave) ---------------
__global__ __launch_bounds__(256) void k_agg32(const __half* __restrict__ Hp,
                                               const float* __restrict__ dinv,
                                               const int* __restrict__ rowptr,
                                               const int* __restrict__ adj,
                                               const float* __restrict__ bias,
                                               float* __restrict__ OUT, int n) {
    const int l = threadIdx.x & 63;
    const int li = l & 7;
    const int node = blockIdx.x * 32 + (threadIdx.x >> 6) * 8 + (l >> 3);
    const int nodec = node < n ? node : n - 1;
    const float dn = dinv[nodec];
    const int e0 = rowptr[nodec];
    const int deg = rowptr[nodec + 1] - e0;
    const f16x4* __restrict__ H4 = (const f16x4*)Hp;  // 8 f16x4 per row

    int dmax = deg;
    dmax = max(dmax, __shfl_xor(dmax, 8, 64));
    dmax = max(dmax, __shfl_xor(dmax, 16, 64));
    dmax = max(dmax, __shfl_xor(dmax, 32, 64));

    const __half2 one2 = __float2half2_rn(1.f);
    const __half2 zero2 = __float2half2_rn(0.f);

    int vs = 0;
    if (deg > 0) vs = adj[min(e0 + li, e0 + deg - 1)];

    __half2 hacc[2];
    {
        f16x4 v = H4[(size_t)nodec * 8 + li];
        const __half2* vh = (const __half2*)&v;
        hacc[0] = vh[0];
        hacc[1] = vh[1];
    }

    const int gbase = l & 56;
    for (int j = 0; j < dmax; j += 2) {
        int s0 = __shfl(vs, gbase | (j & 7), 64);
        int s1 = __shfl(vs, gbase | ((j + 1) & 7), 64);
        __half2 w0 = (j < deg) ? one2 : zero2;
        __half2 w1 = (j + 1 < deg) ? one2 : zero2;
        f16x4 v0 = H4[(size_t)s0 * 8 + li];
        f16x4 v1 = H4[(size_t)s1 * 8 + li];
        if ((j & 7) == 6 && j + 2 < dmax && deg > 0)
            vs = adj[min(e0 + j + 2 + li, e0 + deg - 1)];  // refill next 8
        const __half2* vh0 = (const __half2*)&v0;
        const __half2* vh1 = (const __half2*)&v1;
        hacc[0] = __hfma2(vh0[0], w0, hacc[0]);
        hacc[1] = __hfma2(vh0[1], w0, hacc[1]);
        hacc[0] = __hfma2(vh1[0], w1, hacc[0]);
        hacc[1] = __hfma2(vh1[1], w1, hacc[1]);
    }

    if (node < n) {  // lane li owns features 4li..4li+3 of its node
        float2 f0 = __half22float2(hacc[0]);
        float2 f1 = __half22float2(hacc[1]);
        float4 bv = ((const float4*)bias)[li];
        float4 o = make_float4(f0.x * dn + bv.x, f0.y * dn + bv.y,
                               f1.x * dn + bv.z, f1.y * dn + bv.w);
        ((float4*)(OUT + (size_t)node * 32))[li] = o;
    }
}

// --- fused per-graph max+mean pool + log_softmax (block per graph) -------------
__global__ __launch_bounds__(256) void k_poollsm(const float* __restrict__ A,
                                                 const int* __restrict__ gstart,
                                                 float* __restrict__ out) {
    int g = blockIdx.x;
    int s0 = gstart[g], s1 = gstart[g + 1];
    int c = threadIdx.x & 31, k = threadIdx.x >> 5;
    float mx = -INFINITY, sm = 0.f;
    for (int nidx = s0 + k; nidx < s1; nidx += 8) {
        float v = A[(size_t)nidx * 32 + c];
        mx = fmaxf(mx, v);
        sm += v;
    }
    __shared__ float smx[8][32], ssm[8][32], pooled[64];
    smx[k][c] = mx;
    ssm[k][c] = sm;
    __syncthreads();
    if (threadIdx.x < 32) {
        float M = smx[0][c], S = ssm[0][c];
        #pragma unroll
        for (int kk = 1; kk < 8; ++kk) {
            M = fmaxf(M, smx[kk][c]);
            S += ssm[kk][c];
        }
        int cnt = s1 - s0;
        pooled[c] = M;
        pooled[32 + c] = S / fmaxf((float)cnt, 1.0f);
    }
    __syncthreads();
    if (threadIdx.x < 64) {   // first wave: 64-wide log_softmax
        int l = threadIdx.x;
        float v = pooled[l];
        float m = v;
        #pragma unroll
        for (int o = 32; o > 0; o >>= 1) m = fmaxf(m, __shfl_xor(m, o, 64));
        float e = __expf(v - m);
        float s = e;
        #pragma unroll
        for (int o = 32; o > 0; o >>= 1) s += __shfl_xor(s, o, 64);
        out[g * 64 + l] = v - m - __logf(s);
    }
}

// ---------------------------------------------------------------------------
extern "C" void kernel_launch(void* const* d_in, const int* in_sizes, int n_in,
                              void* d_out, int out_size, void* d_ws, size_t ws_size,
                              hipStream_t stream) {
    const float* x  = (const float*)d_in[0];
    const float* W0 = (const float*)d_in[1];
    const float* b0 = (const float*)d_in[2];
    const float* W1 = (const float*)d_in[3];
    const float* b1 = (const float*)d_in[4];
    const float* W2 = (const float*)d_in[5];
    const float* b2 = (const float*)d_in[6];
    const int* ei_raw    = (const int*)d_in[7];
    const int* batch_raw = (const int*)d_in[8];

    const int N = in_sizes[0] / 96;
    const int E = in_sizes[7] / 2;
    const int G = out_size / 64;
    const int NBUK = (N + 255) >> 8;          // 256 nodes/bucket, <=512 buckets
    float* out = (float*)d_out;

    char* ws = (char*)d_ws;
    size_t off = 0;
    auto alloc = [&](size_t bytes) -> void* {
        void* p = ws + off;
        off += (bytes + 255) & ~(size_t)255;
        return p;
    };
    __half*   Hp96    = (__half*)alloc((size_t)N * 96 * 2);   // gather table, 192B rows
    __half*   As16    = (__half*)alloc((size_t)N * 96 * 2);   // agg out, fp16 natural
    __half*   Hp32    = (__half*)alloc((size_t)N * 32 * 2);   // layer-2 table, 64B rows
    float*    D32     = (float*)alloc((size_t)N * 32 * 4);    // layer-2 agg out
    float*    dinv    = (float*)alloc((size_t)N * 4);
    int*      rowptr  = (int*)alloc((size_t)(N + 1) * 4);
    int*      adj     = (int*)alloc((size_t)E * 4);
    unsigned* ebuk    = (unsigned*)alloc((size_t)E * 4);      // bucket-sorted packed edges
    int*      bcnt    = (int*)alloc(512 * 4);
    int*      bstart  = (int*)alloc(513 * 4);
    int*      gcursor = (int*)alloc(512 * 4);
    int*      flag    = (int*)alloc(256);
    int*      gstart  = (int*)alloc((size_t)(G + 1) * 4);
    __half*   WT      = (__half*)alloc((size_t)21504 * 2);    // W0^T|W1^T|W2^T fp16

    (void)hipMemsetAsync(bcnt, 0, 512 * 4, stream);
    (void)hipMemsetAsync(gcursor, 0, 512 * 4, stream);

    // index dtype detection (conversion folded into consumers)
    k_detect<<<1, 256, 0, stream>>>(ei_raw, flag);

    // weight transpose+convert (one kernel for all 3)
    k_wt3<<<(21504 + 255) / 256, 256, 0, stream>>>(W0, W1, W2, WT);

    // CSR via bucket sort (reads raw edge indices directly)
    const int P2B = (E + 8191) / 8192;
    k_p1hist<<<P2B, 512, 0, stream>>>(ei_raw, flag, bcnt, E, NBUK);
    k_bscan<<<1, 512, 0, stream>>>(bcnt, bstart, NBUK, E);
    k_p2scatter<<<P2B, 512, 0, stream>>>(ei_raw, flag, bstart, gcursor, ebuk, E, NBUK);
    k_p3sort<<<NBUK, 256, 0, stream>>>(ebuk, bstart, adj, rowptr, dinv, N, E);
    k_gstart<<<1, 256, 0, stream>>>(batch_raw, flag, gstart, N, G);

    const int GB = (N + 63) / 64;
    const int AB96 = (N + 15) / 16;   // 16 nodes per agg96 block (4/wave)
    const int AB32 = (N + 31) / 32;   // 32 nodes per agg32 block (8/wave)

    // layer 0: A = x fp32
    k_gemm_mfma<96, false><<<GB, 256, 0, stream>>>(x, (const __half*)nullptr, WT, dinv, Hp96, N);
    k_agg96<true><<<AB96, 256, 0, stream>>>(Hp96, dinv, rowptr, adj, b0, As16, N);
    // layer 1: A = As16 fp16
    k_gemm_mfma<96, true><<<GB, 256, 0, stream>>>((const float*)nullptr, As16, WT + 9216, dinv, Hp96, N);
    k_agg96<true><<<AB96, 256, 0, stream>>>(Hp96, dinv, rowptr, adj, b1, As16, N);
    // layer 2: A = As16 fp16
    k_gemm_mfma<32, true><<<GB, 256, 0, stream>>>((const float*)nullptr, As16, WT + 18432, dinv, Hp32, N);
    k_agg32<<<AB32, 256, 0, stream>>>(Hp32, dinv, rowptr, adj, b2, D32, N);

    // fused pooling + log_softmax
    k_poollsm<<<G, 256, 0, stream>>>(D32, gstart, out);
}

// Round 16
// 200.184 us; speedup vs baseline: 1.4710x; 1.0277x over previous
//
#include <hip/hip_runtime.h>
#include <hip/hip_fp16.h>
#include <math.h>

// ---------------------------------------------------------------------------
// GCN: 3x (MFMA-fp16 GEMM -> sym-normalized neighbor aggregate) with SiLU,
// then per-graph max+mean pool and log_softmax.
// Round 16: round-15 structure (one node per 16-lane quarter) with the agg
// gather loop unrolled 4x: 4 independent row-gathers in flight per lane
// before any FMA (was 2), refill check 1/4 as often. Latency-bound loop ->
// deeper MLP. Everything else unchanged.
// ---------------------------------------------------------------------------

typedef _Float16 f16x8 __attribute__((ext_vector_type(8)));
typedef _Float16 f16x4 __attribute__((ext_vector_type(4)));
typedef float f32x4 __attribute__((ext_vector_type(4)));

static __device__ __forceinline__ float silu_f(float v) {
    return v / (1.0f + __expf(-v));
}

// raw index read honoring int64 (flagged) or int32 layout
static __device__ __forceinline__ int raw_at(const int* __restrict__ raw,
                                             int idx, int f64) {
    return raw[f64 ? 2 * idx : idx];
}

// --- int64-vs-int32 input detection -----------------------------------------
__global__ __launch_bounds__(256) void k_detect(const int* __restrict__ raw,
                                                int* __restrict__ flag) {
    __shared__ int anynz;
    if (threadIdx.x == 0) anynz = 0;
    __syncthreads();
    if (raw[2 * threadIdx.x + 1] != 0) anynz = 1;  // benign race, same value
    __syncthreads();
    if (threadIdx.x == 0) *flag = (anynz ? 0 : 1); // 1 => int64
}

// --- CSR pass 1: bucket histogram (bucket = dst>>8, <=512 buckets) -----------
__global__ __launch_bounds__(512) void k_p1hist(const int* __restrict__ eraw,
                                                const int* __restrict__ flag,
                                                int* __restrict__ bcnt,
                                                int E, int nbuk) {
    __shared__ int hs[512];
    const int t = threadIdx.x;
    const int f64 = flag[0];
    hs[t] = 0;
    __syncthreads();
    const int base = blockIdx.x * 8192;
    const int lim = min(base + 8192, E);
    for (int j = base + t; j < lim; j += 512)
        atomicAdd(&hs[raw_at(eraw, E + j, f64) >> 8], 1);
    __syncthreads();
    if (t < nbuk && hs[t]) atomicAdd(&bcnt[t], hs[t]);
}

// --- CSR pass 1b: exclusive scan of bucket counts -> bstart ------------------
__global__ __launch_bounds__(512) void k_bscan(const int* __restrict__ bcnt,
                                               int* __restrict__ bstart,
                                               int nbuk, int E) {
    __shared__ int lds[512];
    int t = threadIdx.x;
    int v = (t < nbuk) ? bcnt[t] : 0;
    lds[t] = v;
    __syncthreads();
    for (int off = 1; off < 512; off <<= 1) {
        int y = (t >= off) ? lds[t - off] : 0;
        __syncthreads();
        lds[t] += y;
        __syncthreads();
    }
    if (t < nbuk) bstart[t] = lds[t] - v;
    if (t == 0) bstart[nbuk] = E;
}

// --- CSR pass 2: bucket scatter, block-staged ---------------------------------
__global__ __launch_bounds__(512) void k_p2scatter(const int* __restrict__ eraw,
                                                   const int* __restrict__ flag,
                                                   const int* __restrict__ bstart,
                                                   int* __restrict__ gcursor,
                                                   unsigned* __restrict__ ebuk,
                                                   int E, int nbuk) {
    __shared__ int hs[512], sc[512], lexcl[512], pl[512], gb[512];
    __shared__ unsigned stg[8192];
    __shared__ unsigned short stb[8192];
    const int t = threadIdx.x;
    const int f64 = flag[0];
    const int base = blockIdx.x * 8192;
    const int len = min(8192, E - base);

    hs[t] = 0;
    __syncthreads();
    for (int j = t; j < len; j += 512)
        atomicAdd(&hs[raw_at(eraw, E + base + j, f64) >> 8], 1);
    __syncthreads();

    int cv = (t < nbuk) ? hs[t] : 0;
    sc[t] = cv;
    __syncthreads();
    for (int off = 1; off < 512; off <<= 1) {
        int y = (t >= off) ? sc[t - off] : 0;
        __syncthreads();
        sc[t] += y;
        __syncthreads();
    }
    int ex = sc[t] - cv;
    if (t < nbuk) {
        lexcl[t] = ex;
        pl[t] = ex;
        gb[t] = cv ? atomicAdd(&gcursor[t], cv) : 0;
    }
    __syncthreads();

    for (int j = t; j < len; j += 512) {
        int d = raw_at(eraw, E + base + j, f64);
        int s = raw_at(eraw, base + j, f64);
        int b = d >> 8;
        int slot = atomicAdd(&pl[b], 1);
        stg[slot] = ((unsigned)s << 8) | (unsigned)(d & 255);
        stb[slot] = (unsigned short)b;
    }
    __syncthreads();

    for (int s2 = t; s2 < len; s2 += 512) {
        int b = stb[s2];
        int gpos = bstart[b] + gb[b] + (s2 - lexcl[b]);
        ebuk[gpos] = stg[s2];
    }
}

// --- CSR pass 3: per-bucket counting sort -> adj, rowptr, dinv ----------------
__global__ __launch_bounds__(256) void k_p3sort(const unsigned* __restrict__ ebuk,
                                                const int* __restrict__ bstart,
                                                int* __restrict__ adj,
                                                int* __restrict__ rowptr,
                                                float* __restrict__ dinv,
                                                int n, int E) {
    const int b = blockIdx.x;
    const int t = threadIdx.x;
    const int s0 = bstart[b], s1 = bstart[b + 1];
    __shared__ int cs[256], pl[256];
    cs[t] = 0;
    __syncthreads();
    for (int j = s0 + t; j < s1; j += 256)
        atomicAdd(&cs[ebuk[j] & 255], 1);
    __syncthreads();
    int cv = cs[t];
    pl[t] = cv;
    __syncthreads();
    for (int off = 1; off < 256; off <<= 1) {
        int y = (t >= off) ? pl[t - off] : 0;
        __syncthreads();
        pl[t] += y;
        __syncthreads();
    }
    int ex = pl[t] - cv;
    __syncthreads();
    pl[t] = ex;
    int node = (b << 8) + t;
    if (node < n) {
        rowptr[node] = s0 + ex;
        dinv[node] = rsqrtf((float)cv + 1.0f);  // +1 self loop
    }
    if (b == 0 && t == 0) rowptr[n] = E;
    __syncthreads();
    for (int j = s0 + t; j < s1; j += 256) {
        unsigned p = ebuk[j];
        int slot = atomicAdd(&pl[p & 255], 1);
        adj[s0 + slot] = (int)(p >> 8);
    }
}

// --- per-graph boundaries (batch is sorted; raw int64/int32) -------------------
__global__ __launch_bounds__(256) void k_gstart(const int* __restrict__ braw,
                                                const int* __restrict__ flag,
                                                int* __restrict__ gstart,
                                                int n, int G) {
    int t = threadIdx.x;
    if (t > G) return;
    const int f64 = flag[0];
    int lo = 0, hi = n;
    while (lo < hi) {
        int mid = (lo + hi) >> 1;
        if (raw_at(braw, mid, f64) < t) lo = mid + 1; else hi = mid;
    }
    gstart[t] = lo;
}

// --- fused W transpose + fp16 convert for all 3 weights ------------------------
// WT arena: [0,9216) = W0^T (96x96), [9216,18432) = W1^T, [18432,21504) = W2^T.
__global__ __launch_bounds__(256) void k_wt3(const float* __restrict__ W0,
                                             const float* __restrict__ W1,
                                             const float* __restrict__ W2,
                                             __half* __restrict__ WT) {
    int idx = blockIdx.x * 256 + threadIdx.x;
    if (idx >= 21504) return;
    const float* W;
    int fout, loc;
    if (idx < 9216)       { W = W0; fout = 96; loc = idx; }
    else if (idx < 18432) { W = W1; fout = 96; loc = idx - 9216; }
    else                  { W = W2; fout = 32; loc = idx - 18432; }
    int nn = loc / 96, kk = loc - nn * 96;
    WT[idx] = __float2half(W[kk * fout + nn]);
}

// --- MFMA GEMM: H[r,:] = fp16( dinv[r] * (A[r,:96] @ W) ), LDS-free ----------
template <int FOUT, bool AHALF>
__global__ __launch_bounds__(256) void k_gemm_mfma(const float* __restrict__ Xf,
                                                   const __half* __restrict__ Xh,
                                                   const __half* __restrict__ WT,
                                                   const float* __restrict__ dinv,
                                                   __half* __restrict__ H, int n) {
    const int l = threadIdx.x & 63;
    const int w = threadIdx.x >> 6;
    const int row0 = blockIdx.x * 64 + w * 16;
    const int lr = l & 15, lg = l >> 4;
    constexpr int NT = FOUT / 16;

    f16x8 bfrag[NT][3];
    #pragma unroll
    for (int t = 0; t < NT; ++t)
        #pragma unroll
        for (int kk = 0; kk < 3; ++kk)
            bfrag[t][kk] = *(const f16x8*)&WT[(t * 16 + lr) * 96 + kk * 32 + lg * 8];

    f32x4 acc[NT];
    #pragma unroll
    for (int t = 0; t < NT; ++t) acc[t] = (f32x4){0.f, 0.f, 0.f, 0.f};

    int arow = row0 + lr;
    int arow_c = arow < n ? arow : n - 1;  // clamp; garbage rows never stored

    #pragma unroll
    for (int kk = 0; kk < 3; ++kk) {
        f16x8 af;
        if (AHALF) {
            af = *(const f16x8*)(Xh + (size_t)arow_c * 96 + kk * 32 + lg * 8);
        } else {
            const float* xr = Xf + (size_t)arow_c * 96;
            float4 u0 = *(const float4*)&xr[kk * 32 + lg * 8];
            float4 u1 = *(const float4*)&xr[kk * 32 + lg * 8 + 4];
            af[0] = (_Float16)u0.x; af[1] = (_Float16)u0.y;
            af[2] = (_Float16)u0.z; af[3] = (_Float16)u0.w;
            af[4] = (_Float16)u1.x; af[5] = (_Float16)u1.y;
            af[6] = (_Float16)u1.z; af[7] = (_Float16)u1.w;
        }
        #pragma unroll
        for (int t = 0; t < NT; ++t)
            acc[t] = __builtin_amdgcn_mfma_f32_16x16x32_f16(af, bfrag[t][kk], acc[t], 0, 0, 0);
    }

    // C/D: col = t*16+lr, row = row0 + lg*4 + i  (m89-verified map)
    #pragma unroll
    for (int i = 0; i < 4; ++i) {
        int r = row0 + lg * 4 + i;
        if (r < n) {
            float dv = dinv[r];
            #pragma unroll
            for (int t = 0; t < NT; ++t)
                H[(size_t)r * FOUT + t * 16 + lr] = __float2half(acc[t][i] * dv);
        }
    }
}

// --- aggregation, F=96: ONE NODE PER QUARTER (4 nodes/wave), 4x unroll ---------
// Quarter q = l>>4 owns node base+q; lane li = l&15: li<12 loads octet li of
// the gathered row (f16x8); li>=12 clamps to octet li-12 (broadcast, unused).
// Quarter's next 16 edges staged in its lanes; 4 edges (4 independent
// gathers) per iteration; refill every 16 edges. fp16 packed accumulation.
template <bool SILU>
__global__ __launch_bounds__(256) void k_agg96(const __half* __restrict__ Hp,
                                               const float* __restrict__ dinv,
                                               const int* __restrict__ rowptr,
                                               const int* __restrict__ adj,
                                               const float* __restrict__ bias,
                                               __half* __restrict__ OUT, int n) {
    const int l = threadIdx.x & 63;
    const int li = l & 15;
    const int oct = li < 12 ? li : li - 12;
    const int node = blockIdx.x * 16 + (threadIdx.x >> 6) * 4 + (l >> 4);
    const int nodec = node < n ? node : n - 1;
    const float dn = dinv[nodec];
    const int e0 = rowptr[nodec];
    const int deg = rowptr[nodec + 1] - e0;
    const f16x8* __restrict__ H8 = (const f16x8*)Hp;  // 12 f16x8 per row

    // wave-max degree across the 4 quarters
    int dmax = deg;
    dmax = max(dmax, __shfl_xor(dmax, 16, 64));
    dmax = max(dmax, __shfl_xor(dmax, 32, 64));

    const __half2 one2 = __float2half2_rn(1.f);
    const __half2 zero2 = __float2half2_rn(0.f);

    // stage this quarter's next 16 edges (clamped; deg=0 -> row 0, masked)
    int vs = 0;
    if (deg > 0) vs = adj[min(e0 + li, e0 + deg - 1)];

    // init accumulator with self row (once per quarter = once per node)
    __half2 hacc[4];
    {
        f16x8 v = H8[(size_t)nodec * 12 + oct];
        const __half2* vh = (const __half2*)&v;
        #pragma unroll
        for (int i = 0; i < 4; ++i) hacc[i] = vh[i];
    }

    const int qbase = l & 48;
    for (int j = 0; j < dmax; j += 4) {
        int s0 = __shfl(vs, qbase | (j & 15), 64);
        int s1 = __shfl(vs, qbase | ((j + 1) & 15), 64);
        int s2 = __shfl(vs, qbase | ((j + 2) & 15), 64);
        int s3 = __shfl(vs, qbase | ((j + 3) & 15), 64);
        __half2 w0 = (j < deg) ? one2 : zero2;
        __half2 w1 = (j + 1 < deg) ? one2 : zero2;
        __half2 w2 = (j + 2 < deg) ? one2 : zero2;
        __half2 w3 = (j + 3 < deg) ? one2 : zero2;
        f16x8 v0 = H8[(size_t)s0 * 12 + oct];   // 4 gathers in flight
        f16x8 v1 = H8[(size_t)s1 * 12 + oct];
        f16x8 v2 = H8[(size_t)s2 * 12 + oct];
        f16x8 v3 = H8[(size_t)s3 * 12 + oct];
        if ((j & 15) == 12 && j + 4 < dmax && deg > 0)
            vs = adj[min(e0 + j + 4 + li, e0 + deg - 1)];  // refill next 16
        const __half2* vh0 = (const __half2*)&v0;
        const __half2* vh1 = (const __half2*)&v1;
        const __half2* vh2 = (const __half2*)&v2;
        const __half2* vh3 = (const __half2*)&v3;
        #pragma unroll
        for (int i = 0; i < 4; ++i) hacc[i] = __hfma2(vh0[i], w0, hacc[i]);
        #pragma unroll
        for (int i = 0; i < 4; ++i) hacc[i] = __hfma2(vh1[i], w1, hacc[i]);
        #pragma unroll
        for (int i = 0; i < 4; ++i) hacc[i] = __hfma2(vh2[i], w2, hacc[i]);
        #pragma unroll
        for (int i = 0; i < 4; ++i) hacc[i] = __hfma2(vh3[i], w3, hacc[i]);
    }

    if (li < 12 && node < n) {  // lane li owns features 8li..8li+7 of its node
        float acc[8];
        #pragma unroll
        for (int i = 0; i < 4; ++i) {
            float2 f = __half22float2(hacc[i]);
            acc[2 * i] = f.x;
            acc[2 * i + 1] = f.y;
        }
        float4 bv0 = ((const float4*)bias)[2 * li];
        float4 bv1 = ((const float4*)bias)[2 * li + 1];
        float o0 = acc[0] * dn + bv0.x, o1 = acc[1] * dn + bv0.y;
        float o2 = acc[2] * dn + bv0.z, o3 = acc[3] * dn + bv0.w;
        float o4 = acc[4] * dn + bv1.x, o5 = acc[5] * dn + bv1.y;
        float o6 = acc[6] * dn + bv1.z, o7 = acc[7] * dn + bv1.w;
        if (SILU) {
            o0 = silu_f(o0); o1 = silu_f(o1); o2 = silu_f(o2); o3 = silu_f(o3);
            o4 = silu_f(o4); o5 = silu_f(o5); o6 = silu_f(o6); o7 = silu_f(o7);
        }
        f16x8 wv = {(_Float16)o0, (_Float16)o1, (_Float16)o2, (_Float16)o3,
                    (_Float16)o4, (_Float16)o5, (_Float16)o6, (_Float16)o7};
        *(f16x8*)(OUT + (size_t)node * 96 + li * 8) = wv;
    }
}

// --- aggregation, F=32: ONE NODE PER 8-LANE GROUP (8 nodes/wave), 4x unroll ----
__global__ __launch_bounds__(256) void k_agg32(const __half* __restrict__ Hp,
                                               const float* __restrict__ dinv,
                                               const int* __restrict__ rowptr,
                                               const int* __restrict__ adj,
                                               const float* __restrict__ bias,
                                               float* __restrict__ OUT, int n) {
    const int l = threadIdx.x & 63;
    const int li = l & 7;
    const int node = blockIdx.x * 32 + (threadIdx.x >> 6) * 8 + (l >> 3);
    const int nodec = node < n ? node : n - 1;
    const float dn = dinv[nodec];
    const int e0 = rowptr[nodec];
    const int deg = rowptr[nodec + 1] - e0;
    const f16x4* __restrict__ H4 = (const f16x4*)Hp;  // 8 f16x4 per row

    int dmax = deg;
    dmax = max(dmax, __shfl_xor(dmax, 8, 64));
    dmax = max(dmax, __shfl_xor(dmax, 16, 64));
    dmax = max(dmax, __shfl_xor(dmax, 32, 64));

    const __half2 one2 = __float2half2_rn(1.f);
    const __half2 zero2 = __float2half2_rn(0.f);

    int vs = 0;
    if (deg > 0) vs = adj[min(e0 + li, e0 + deg - 1)];

    __half2 hacc[2];
    {
        f16x4 v = H4[(size_t)nodec * 8 + li];
        const __half2* vh = (const __half2*)&v;
        hacc[0] = vh[0];
        hacc[1] = vh[1];
    }

    const int gbase = l & 56;
    for (int j = 0; j < dmax; j += 4) {
        int s0 = __shfl(vs, gbase | (j & 7), 64);
        int s1 = __shfl(vs, gbase | ((j + 1) & 7), 64);
        int s2 = __shfl(vs, gbase | ((j + 2) & 7), 64);
        int s3 = __shfl(vs, gbase | ((j + 3) & 7), 64);
        __half2 w0 = (j < deg) ? one2 : zero2;
        __half2 w1 = (j + 1 < deg) ? one2 : zero2;
        __half2 w2 = (j + 2 < deg) ? one2 : zero2;
        __half2 w3 = (j + 3 < deg) ? one2 : zero2;
        f16x4 v0 = H4[(size_t)s0 * 8 + li];
        f16x4 v1 = H4[(size_t)s1 * 8 + li];
        f16x4 v2 = H4[(size_t)s2 * 8 + li];
        f16x4 v3 = H4[(size_t)s3 * 8 + li];
        if ((j & 7) == 4 && j + 4 < dmax && deg > 0)
            vs = adj[min(e0 + j + 4 + li, e0 + deg - 1)];  // refill next 8
        const __half2* vh0 = (const __half2*)&v0;
        const __half2* vh1 = (const __half2*)&v1;
        const __half2* vh2 = (const __half2*)&v2;
        const __half2* vh3 = (const __half2*)&v3;
        hacc[0] = __hfma2(vh0[0], w0, hacc[0]);
        hacc[1] = __hfma2(vh0[1], w0, hacc[1]);
        hacc[0] = __hfma2(vh1[0], w1, hacc[0]);
        hacc[1] = __hfma2(vh1[1], w1, hacc[1]);
        hacc[0] = __hfma2(vh2[0], w2, hacc[0]);
        hacc[1] = __hfma2(vh2[1], w2, hacc[1]);
        hacc[0] = __hfma2(vh3[0], w3, hacc[0]);
        hacc[1] = __hfma2(vh3[1], w3, hacc[1]);
    }

    if (node < n) {  // lane li owns features 4li..4li+3 of its node
        float2 f0 = __half22float2(hacc[0]);
        float2 f1 = __half22float2(hacc[1]);
        float4 bv = ((const float4*)bias)[li];
        float4 o = make_float4(f0.x * dn + bv.x, f0.y * dn + bv.y,
                               f1.x * dn + bv.z, f1.y * dn + bv.w);
        ((float4*)(OUT + (size_t)node * 32))[li] = o;
    }
}

// --- fused per-graph max+mean pool + log_softmax (block per graph) -------------
__global__ __launch_bounds__(256) void k_poollsm(const float* __restrict__ A,
                                                 const int* __restrict__ gstart,
                                                 float* __restrict__ out) {
    int g = blockIdx.x;
    int s0 = gstart[g], s1 = gstart[g + 1];
    int c = threadIdx.x & 31, k = threadIdx.x >> 5;
    float mx = -INFINITY, sm = 0.f;
    for (int nidx = s0 + k; nidx < s1; nidx += 8) {
        float v = A[(size_t)nidx * 32 + c];
        mx = fmaxf(mx, v);
        sm += v;
    }
    __shared__ float smx[8][32], ssm[8][32], pooled[64];
    smx[k][c] = mx;
    ssm[k][c] = sm;
    __syncthreads();
    if (threadIdx.x < 32) {
        float M = smx[0][c], S = ssm[0][c];
        #pragma unroll
        for (int kk = 1; kk < 8; ++kk) {
            M = fmaxf(M, smx[kk][c]);
            S += ssm[kk][c];
        }
        int cnt = s1 - s0;
        pooled[c] = M;
        pooled[32 + c] = S / fmaxf((float)cnt, 1.0f);
    }
    __syncthreads();
    if (threadIdx.x < 64) {   // first wave: 64-wide log_softmax
        int l = threadIdx.x;
        float v = pooled[l];
        float m = v;
        #pragma unroll
        for (int o = 32; o > 0; o >>= 1) m = fmaxf(m, __shfl_xor(m, o, 64));
        float e = __expf(v - m);
        float s = e;
        #pragma unroll
        for (int o = 32; o > 0; o >>= 1) s += __shfl_xor(s, o, 64);
        out[g * 64 + l] = v - m - __logf(s);
    }
}

// ---------------------------------------------------------------------------
extern "C" void kernel_launch(void* const* d_in, const int* in_sizes, int n_in,
                              void* d_out, int out_size, void* d_ws, size_t ws_size,
                              hipStream_t stream) {
    const float* x  = (const float*)d_in[0];
    const float* W0 = (const float*)d_in[1];
    const float* b0 = (const float*)d_in[2];
    const float* W1 = (const float*)d_in[3];
    const float* b1 = (const float*)d_in[4];
    const float* W2 = (const float*)d_in[5];
    const float* b2 = (const float*)d_in[6];
    const int* ei_raw    = (const int*)d_in[7];
    const int* batch_raw = (const int*)d_in[8];

    const int N = in_sizes[0] / 96;
    const int E = in_sizes[7] / 2;
    const int G = out_size / 64;
    const int NBUK = (N + 255) >> 8;          // 256 nodes/bucket, <=512 buckets
    float* out = (float*)d_out;

    char* ws = (char*)d_ws;
    size_t off = 0;
    auto alloc = [&](size_t bytes) -> void* {
        void* p = ws + off;
        off += (bytes + 255) & ~(size_t)255;
        return p;
    };
    __half*   Hp96    = (__half*)alloc((size_t)N * 96 * 2);   // gather table, 192B rows
    __half*   As16    = (__half*)alloc((size_t)N * 96 * 2);   // agg out, fp16 natural
    __half*   Hp32    = (__half*)alloc((size_t)N * 32 * 2);   // layer-2 table, 64B rows
    float*    D32     = (float*)alloc((size_t)N * 32 * 4);    // layer-2 agg out
    float*    dinv    = (float*)alloc((size_t)N * 4);
    int*      rowptr  = (int*)alloc((size_t)(N + 1) * 4);
    int*      adj     = (int*)alloc((size_t)E * 4);
    unsigned* ebuk    = (unsigned*)alloc((size_t)E * 4);      // bucket-sorted packed edges
    int*      bcnt    = (int*)alloc(512 * 4);
    int*      bstart  = (int*)alloc(513 * 4);
    int*      gcursor = (int*)alloc(512 * 4);
    int*      flag    = (int*)alloc(256);
    int*      gstart  = (int*)alloc((size_t)(G + 1) * 4);
    __half*   WT      = (__half*)alloc((size_t)21504 * 2);    // W0^T|W1^T|W2^T fp16

    (void)hipMemsetAsync(bcnt, 0, 512 * 4, stream);
    (void)hipMemsetAsync(gcursor, 0, 512 * 4, stream);

    // index dtype detection (conversion folded into consumers)
    k_detect<<<1, 256, 0, stream>>>(ei_raw, flag);

    // weight transpose+convert (one kernel for all 3)
    k_wt3<<<(21504 + 255) / 256, 256, 0, stream>>>(W0, W1, W2, WT);

    // CSR via bucket sort (reads raw edge indices directly)
    const int P2B = (E + 8191) / 8192;
    k_p1hist<<<P2B, 512, 0, stream>>>(ei_raw, flag, bcnt, E, NBUK);
    k_bscan<<<1, 512, 0, stream>>>(bcnt, bstart, NBUK, E);
    k_p2scatter<<<P2B, 512, 0, stream>>>(ei_raw, flag, bstart, gcursor, ebuk, E, NBUK);
    k_p3sort<<<NBUK, 256, 0, stream>>>(ebuk, bstart, adj, rowptr, dinv, N, E);
    k_gstart<<<1, 256, 0, stream>>>(batch_raw, flag, gstart, N, G);

    const int GB = (N + 63) / 64;
    const int AB96 = (N + 15) / 16;   // 16 nodes per agg96 block (4/wave)
    const int AB32 = (N + 31) / 32;   // 32 nodes per agg32 block (8/wave)

    // layer 0: A = x fp32
    k_gemm_mfma<96, false><<<GB, 256, 0, stream>>>(x, (const __half*)nullptr, WT, dinv, Hp96, N);
    k_agg96<true><<<AB96, 256, 0, stream>>>(Hp96, dinv, rowptr, adj, b0, As16, N);
    // layer 1: A = As16 fp16
    k_gemm_mfma<96, true><<<GB, 256, 0, stream>>>((const float*)nullptr, As16, WT + 9216, dinv, Hp96, N);
    k_agg96<true><<<AB96, 256, 0, stream>>>(Hp96, dinv, rowptr, adj, b1, As16, N);
    // layer 2: A = As16 fp16
    k_gemm_mfma<32, true><<<GB, 256, 0, stream>>>((const float*)nullptr, As16, WT + 18432, dinv, Hp32, N);
    k_agg32<<<AB32, 256, 0, stream>>>(Hp32, dinv, rowptr, adj, b2, D32, N);

    // fused pooling + log_softmax
    k_poollsm<<<G, 256, 0, stream>>>(D32, gstart, out);
}